// Round 10
// baseline (197.507 us; speedup 1.0000x reference)
//
#include <hip/hip_runtime.h>
#include <math.h>

#define B_ 8
#define L_ 2048
#define D_ 512
#define LOG2L 11
#define TOPK 7
#define M_ (B_ * L_)     // 16384

typedef __attribute__((ext_vector_type(8))) _Float16 half8;
typedef __attribute__((ext_vector_type(4))) _Float16 half4;
typedef __attribute__((ext_vector_type(4))) float f32x4;

// ------------------------------------------------------------------
// convw: 4 weight mats fp32 [512][512] (k-major) -> f16 [n][k].
// ------------------------------------------------------------------
__global__ __launch_bounds__(256) void convw_kernel(
    const float* __restrict__ W0, const float* __restrict__ W1,
    const float* __restrict__ W2, const float* __restrict__ W3,
    _Float16* __restrict__ T0, _Float16* __restrict__ T1,
    _Float16* __restrict__ T2, _Float16* __restrict__ T3)
{
  __shared__ float tile[64][65];
  const int t = (int)threadIdx.x;
  const int mat = (int)blockIdx.x >> 6;
  const int tb = (int)blockIdx.x & 63;
  const float* W = (mat == 0) ? W0 : (mat == 1) ? W1 : (mat == 2) ? W2 : W3;
  _Float16* Wt = (mat == 0) ? T0 : (mat == 1) ? T1 : (mat == 2) ? T2 : T3;
  const int k0 = (tb >> 3) * 64;
  const int n0 = (tb & 7) * 64;
#pragma unroll
  for (int i = 0; i < 4; ++i) {
    const int kl = (t >> 4) + i * 16;
    const float4 v = *reinterpret_cast<const float4*>(&W[(size_t)(k0 + kl) * D_ + n0 + (t & 15) * 4]);
    tile[kl][(t & 15) * 4 + 0] = v.x;
    tile[kl][(t & 15) * 4 + 1] = v.y;
    tile[kl][(t & 15) * 4 + 2] = v.z;
    tile[kl][(t & 15) * 4 + 3] = v.w;
  }
  __syncthreads();
  const int nl = t >> 2, q = t & 3;
  half8 h0, h1;
#pragma unroll
  for (int j = 0; j < 8; ++j) {
    h0[j] = (_Float16)tile[q * 16 + j][nl];
    h1[j] = (_Float16)tile[q * 16 + 8 + j][nl];
  }
  _Float16* dst = &Wt[(size_t)(n0 + nl) * D_ + k0 + q * 16];
  *reinterpret_cast<half8*>(dst) = h0;
  *reinterpret_cast<half8*>(dst + 8) = h1;
}

// ------------------------------------------------------------------
// MFMA f16 GEMM: C = A[M,512] @ W using Wt[n][k] f16.
// 64x128 tile, BK=32, 4 waves (2x2: wave tile 32x64), grid 1024
// (4 blocks/CU), XCD-swizzled. OUTMODE: 0 = fp32 [M,512]; 2 = f16
// [M,512]; 3 = f16 transposed [512][M] (acc reg idx is m).
// ------------------------------------------------------------------
#define LDSTR 40
#define NWG 1024

template <int INBF, int OUTMODE>
__global__ __launch_bounds__(256) void gemm_f16_kernel(
    const float* __restrict__ Af, const _Float16* __restrict__ Ah,
    const _Float16* __restrict__ Wt,
    float* __restrict__ Cf, _Float16* __restrict__ Ch)
{
  __shared__ __align__(16) _Float16 sA[64 * LDSTR];
  __shared__ __align__(16) _Float16 sB[128 * LDSTR];

  const int bid = (int)blockIdx.x;
  const int wg = (bid & 7) * (NWG >> 3) + (bid >> 3);
  const int m0 = (wg >> 2) << 6;        // 256 m-panels of 64
  const int n0 = (wg & 3) << 7;         // 4 n-panels of 128

  const int tid = (int)threadIdx.x;
  const int lane = tid & 63, wave = tid >> 6;
  const int wr = (wave >> 1) << 5;      // 0 / 32
  const int wc = (wave & 1) << 6;       // 0 / 64

  const int arow = tid >> 2;            // 0..63  (A stage row)
  const int ac0 = (tid & 3) << 3;       // 0,8,16,24
  const int brow = tid >> 1;            // 0..127 (B stage row)
  const int bc0 = (tid & 1) << 4;       // 0 / 16

  f32x4 acc[2][4];
  const f32x4 zero = {0.f, 0.f, 0.f, 0.f};
#pragma unroll
  for (int i = 0; i < 2; ++i)
#pragma unroll
    for (int j = 0; j < 4; ++j) acc[i][j] = zero;

  const int fr = lane & 15;
  const int g8 = (lane >> 4) << 3;

  for (int k0 = 0; k0 < D_; k0 += 32) {
    half8 ha, hb0, hb1;
    if constexpr (INBF == 0) {
      const float* ap = Af + (size_t)(m0 + arow) * D_ + k0 + ac0;
      const float4 v0 = *reinterpret_cast<const float4*>(ap);
      const float4 v1 = *reinterpret_cast<const float4*>(ap + 4);
      ha[0] = (_Float16)v0.x; ha[1] = (_Float16)v0.y;
      ha[2] = (_Float16)v0.z; ha[3] = (_Float16)v0.w;
      ha[4] = (_Float16)v1.x; ha[5] = (_Float16)v1.y;
      ha[6] = (_Float16)v1.z; ha[7] = (_Float16)v1.w;
    } else {
      ha = *reinterpret_cast<const half8*>(Ah + (size_t)(m0 + arow) * D_ + k0 + ac0);
    }
    {
      const _Float16* bp = Wt + (size_t)(n0 + brow) * D_ + k0 + bc0;
      hb0 = *reinterpret_cast<const half8*>(bp);
      hb1 = *reinterpret_cast<const half8*>(bp + 8);
    }

    __syncthreads();    // previous iteration's fragment reads done
    *reinterpret_cast<half8*>(&sA[arow * LDSTR + ac0]) = ha;
    *reinterpret_cast<half8*>(&sB[brow * LDSTR + bc0]) = hb0;
    *reinterpret_cast<half8*>(&sB[brow * LDSTR + bc0 + 8]) = hb1;
    __syncthreads();

    half8 afr[2], bfr[4];
#pragma unroll
    for (int i = 0; i < 2; ++i)
      afr[i] = *reinterpret_cast<const half8*>(&sA[(wr + i * 16 + fr) * LDSTR + g8]);
#pragma unroll
    for (int i = 0; i < 4; ++i)
      bfr[i] = *reinterpret_cast<const half8*>(&sB[(wc + i * 16 + fr) * LDSTR + g8]);
#pragma unroll
    for (int mi = 0; mi < 2; ++mi)
#pragma unroll
      for (int ni = 0; ni < 4; ++ni)
        acc[mi][ni] = __builtin_amdgcn_mfma_f32_16x16x32_f16(afr[mi], bfr[ni], acc[mi][ni], 0, 0, 0);
  }

  const int orow = (lane >> 4) << 2;   // m sub-offset (reg idx r adds 0..3)
  const int ocol = lane & 15;          // n sub-offset
  if constexpr (OUTMODE == 0) {
#pragma unroll
    for (int mi = 0; mi < 2; ++mi)
#pragma unroll
      for (int ni = 0; ni < 4; ++ni)
#pragma unroll
        for (int r = 0; r < 4; ++r)
          Cf[(size_t)(m0 + wr + mi * 16 + orow + r) * D_ + n0 + wc + ni * 16 + ocol] = acc[mi][ni][r];
  } else if constexpr (OUTMODE == 2) {
#pragma unroll
    for (int mi = 0; mi < 2; ++mi)
#pragma unroll
      for (int ni = 0; ni < 4; ++ni)
#pragma unroll
        for (int r = 0; r < 4; ++r)
          Ch[(size_t)(m0 + wr + mi * 16 + orow + r) * D_ + n0 + wc + ni * 16 + ocol] = (_Float16)acc[mi][ni][r];
  } else {
    // CT[n][m] f16: acc[mi][ni] holds 4 consecutive m -> half4 store
#pragma unroll
    for (int ni = 0; ni < 4; ++ni) {
      const size_t nrow = (size_t)(n0 + wc + ni * 16 + ocol) * M_;
#pragma unroll
      for (int mi = 0; mi < 2; ++mi) {
        half4 hv;
        hv[0] = (_Float16)acc[mi][ni][0]; hv[1] = (_Float16)acc[mi][ni][1];
        hv[2] = (_Float16)acc[mi][ni][2]; hv[3] = (_Float16)acc[mi][ni][3];
        *reinterpret_cast<half4*>(&Ch[nrow + m0 + wr + mi * 16 + orow]) = hv;
      }
    }
  }
}

// ------------------------------------------------------------------
// corr_fft v5: 512 threads = 2 independent register FFTs per block
// (group g = tid>>8 owns its own LDS buffer). 2 sequential d per
// group (4 d per block total). Hermitian-half atomics.
// ------------------------------------------------------------------
__device__ __forceinline__ int rev11(int x) {
  return (int)(__brev((unsigned)x) >> (32 - LOG2L));
}

#define NSEQ 2
#define PADI(i) ((i) + ((i) >> 5))

#define BFLY(j0, j1, wr_, wi_) { \
  const float ar = xr[j0], ai = xi[j0], br = xr[j1], bi = xi[j1]; \
  xr[j0] = ar + br; xi[j0] = ai + bi; \
  const float tr = ar - br, ti = ai - bi; \
  xr[j1] = tr * (wr_) - ti * (wi_); \
  xi[j1] = tr * (wi_) + ti * (wr_); }

__global__ __launch_bounds__(512) void corr_fft_kernel(
    const _Float16* __restrict__ qT, const _Float16* __restrict__ kT,
    float* __restrict__ S)
{
  __shared__ float reb[2 * 2112];
  __shared__ float imb[2 * 2112];
  const int tid = (int)threadIdx.x;
  const int g = tid >> 8;                   // FFT slot in block
  const int t = tid & 255;                  // local thread id
  float* re = reb + g * 2112;
  float* im = imb + g * 2112;
  const int blk = (int)blockIdx.x;
  const int b = blk >> 7;                   // 128 chunks per batch
  const int d0 = (blk & 127) * (2 * NSEQ) + g * NSEQ;
  const int u2 = t & 31, u3 = t & 3;

  float w2048r, w2048i, w256r, w256i, w32r, w32i;
  {
    float s_, c_;
    __sincosf(-6.283185307179586f * (float)t / 2048.f, &s_, &c_);
    w2048r = c_; w2048i = s_;
    __sincosf(-6.283185307179586f * (float)u2 / 256.f, &s_, &c_);
    w256r = c_; w256i = s_;
    __sincosf(-6.283185307179586f * (float)u3 / 32.f, &s_, &c_);
    w32r = c_; w32i = s_;
  }
  const float w1024r = w2048r * w2048r - w2048i * w2048i, w1024i = 2.f * w2048r * w2048i;
  const float w512r  = w1024r * w1024r - w1024i * w1024i, w512i  = 2.f * w1024r * w1024i;
  const float w128r  = w256r * w256r - w256i * w256i,     w128i  = 2.f * w256r * w256i;
  const float w64r   = w128r * w128r - w128i * w128i,     w64i   = 2.f * w128r * w128i;
  const float w16r   = w32r * w32r - w32i * w32i,         w16i   = 2.f * w32r * w32i;
  const float w8r    = w16r * w16r - w16i * w16i,         w8i    = 2.f * w16r * w16i;

  const float C_ = 0.70710678118654752f;
  const float W8R[4] = {1.f, C_, 0.f, -C_};
  const float W8I[4] = {0.f, -C_, -1.f, -C_};

  float pr[8] = {}, pi_[8] = {};

  for (int dc = 0; dc < NSEQ; ++dc) {
    const int d = d0 + dc;
    const _Float16* qrow = qT + (size_t)d * M_ + (size_t)b * L_;
    const _Float16* krow = kT + (size_t)d * M_ + (size_t)b * L_;

    float xr[8], xi[8];
#pragma unroll
    for (int j = 0; j < 8; ++j) {
      xr[j] = (float)qrow[t + 256 * j];
      xi[j] = (float)krow[t + 256 * j];
    }

    // ---- round 1: stages half=1024,512,256
#pragma unroll
    for (int j = 0; j < 4; ++j) {
      const float wr_ = w2048r * W8R[j] - w2048i * W8I[j];
      const float wi_ = w2048r * W8I[j] + w2048i * W8R[j];
      BFLY(j, j + 4, wr_, wi_);
    }
#pragma unroll
    for (int base = 0; base < 8; base += 4) {
      BFLY(base + 0, base + 2, w1024r, w1024i);
      BFLY(base + 1, base + 3, w1024i, -w1024r);
    }
#pragma unroll
    for (int a = 0; a < 8; a += 2) BFLY(a, a + 1, w512r, w512i);

    // ---- exchange 1: pos t+256j -> (t>>5)*256 + (t&31) + 32j
    __syncthreads();
#pragma unroll
    for (int j = 0; j < 8; ++j) {
      const int p = t + 256 * j;
      re[PADI(p)] = xr[j]; im[PADI(p)] = xi[j];
    }
    __syncthreads();
#pragma unroll
    for (int j = 0; j < 8; ++j) {
      const int p = ((t >> 5) << 8) + u2 + 32 * j;
      xr[j] = re[PADI(p)]; xi[j] = im[PADI(p)];
    }

    // ---- round 2: stages half=128,64,32
#pragma unroll
    for (int j = 0; j < 4; ++j) {
      const float wr_ = w256r * W8R[j] - w256i * W8I[j];
      const float wi_ = w256r * W8I[j] + w256i * W8R[j];
      BFLY(j, j + 4, wr_, wi_);
    }
#pragma unroll
    for (int base = 0; base < 8; base += 4) {
      BFLY(base + 0, base + 2, w128r, w128i);
      BFLY(base + 1, base + 3, w128i, -w128r);
    }
#pragma unroll
    for (int a = 0; a < 8; a += 2) BFLY(a, a + 1, w64r, w64i);

    // ---- exchange 2 -> (t>>2)*32 + (t&3) + 4j
    __syncthreads();
#pragma unroll
    for (int j = 0; j < 8; ++j) {
      const int p = ((t >> 5) << 8) + u2 + 32 * j;
      re[PADI(p)] = xr[j]; im[PADI(p)] = xi[j];
    }
    __syncthreads();
#pragma unroll
    for (int j = 0; j < 8; ++j) {
      const int p = ((t >> 2) << 5) + u3 + 4 * j;
      xr[j] = re[PADI(p)]; xi[j] = im[PADI(p)];
    }

    // ---- round 3: stages half=16,8,4
#pragma unroll
    for (int j = 0; j < 4; ++j) {
      const float wr_ = w32r * W8R[j] - w32i * W8I[j];
      const float wi_ = w32r * W8I[j] + w32i * W8R[j];
      BFLY(j, j + 4, wr_, wi_);
    }
#pragma unroll
    for (int base = 0; base < 8; base += 4) {
      BFLY(base + 0, base + 2, w16r, w16i);
      BFLY(base + 1, base + 3, w16i, -w16r);
    }
#pragma unroll
    for (int a = 0; a < 8; a += 2) BFLY(a, a + 1, w8r, w8i);

    // ---- exchange 3 -> pos 8t+j
    __syncthreads();
#pragma unroll
    for (int j = 0; j < 8; ++j) {
      const int p = ((t >> 2) << 5) + u3 + 4 * j;
      re[PADI(p)] = xr[j]; im[PADI(p)] = xi[j];
    }
    __syncthreads();
#pragma unroll
    for (int j = 0; j < 8; ++j) {
      const int p = 8 * t + j;
      xr[j] = re[PADI(p)]; xi[j] = im[PADI(p)];
    }

    // ---- round 4: stages half=2,1
#pragma unroll
    for (int base = 0; base < 8; base += 4) {
      BFLY(base + 0, base + 2, 1.f, 0.f);
      BFLY(base + 1, base + 3, 0.f, -1.f);
    }
#pragma unroll
    for (int a = 0; a < 8; a += 2) BFLY(a, a + 1, 1.f, 0.f);

#pragma unroll
    for (int j = 0; j < 8; ++j) {
      const int p = 8 * t + j;
      re[PADI(p)] = xr[j]; im[PADI(p)] = xi[j];
    }
    __syncthreads();

    // ---- Hermitian split + product (pos p holds freq rev11(p))
#pragma unroll
    for (int i = 0; i < 8; ++i) {
      const int p = t + 256 * i;
      const int f = rev11(p);
      const int fm = (L_ - f) & (L_ - 1);
      const int pm = rev11(fm);
      const float Ar = re[PADI(p)],  Ai = im[PADI(p)];
      const float Br = re[PADI(pm)], Bi = -im[PADI(pm)];
      const float Qr = 0.5f * (Ar + Br), Qi = 0.5f * (Ai + Bi);
      const float Cr = 0.5f * (Ai - Bi), Ci = 0.5f * (Ar - Br);
      pr[i]  += Qr * Cr - Qi * Ci;
      pi_[i] += Qr * Ci + Qi * Cr;
    }
    if (dc + 1 < NSEQ) __syncthreads();
  }

  // only the non-redundant half: P[L-f] = conj(P[f])
#pragma unroll
  for (int i = 0; i < 8; ++i) {
    const int p = t + 256 * i;
    const int f = rev11(p);
    if (f <= L_ / 2) {
      atomicAdd(&S[((size_t)b * L_ + p) * 2 + 0], pr[i]);
      atomicAdd(&S[((size_t)b * L_ + p) * 2 + 1], pi_[i]);
    }
  }
}

// ------------------------------------------------------------------
// Inverse DIT (bit-rev in, natural out), per b, 1024 threads
// (1 butterfly per thread per stage). Reconstructs conjugate half.
// ------------------------------------------------------------------
__global__ __launch_bounds__(1024) void ifft_kernel(
    const float* __restrict__ S, float* __restrict__ mv)
{
  __shared__ float re[L_];
  __shared__ float im[L_];
  const int b = blockIdx.x;
  for (int p = (int)threadIdx.x; p < L_; p += 1024) {
    const int f = rev11(p);
    float sr, si;
    if (f <= L_ / 2) {
      sr = S[((size_t)b * L_ + p) * 2 + 0];
      si = S[((size_t)b * L_ + p) * 2 + 1];
    } else {
      const int pm = rev11(L_ - f);
      sr = S[((size_t)b * L_ + pm) * 2 + 0];
      si = -S[((size_t)b * L_ + pm) * 2 + 1];
    }
    re[p] = sr; im[p] = si;
  }
  __syncthreads();
  for (int s = 1; s <= LOG2L; ++s) {
    const int half = 1 << (s - 1);
    {
      const int j = (int)threadIdx.x;
      const int pos = j & (half - 1);
      const int i0 = ((j >> (s - 1)) << s) + pos;
      const int i1 = i0 + half;
      const float ang = 3.14159265358979323846f * (float)pos / (float)half;
      float wi, wr;
      __sincosf(ang, &wi, &wr);
      const float br = re[i1], bi = im[i1];
      const float tr = br * wr - bi * wi;
      const float ti = br * wi + bi * wr;
      const float ar = re[i0], ai = im[i0];
      re[i0] = ar + tr; im[i0] = ai + ti;
      re[i1] = ar - tr; im[i1] = ai - ti;
    }
    __syncthreads();
  }
  const float scale = 1.0f / ((float)D_ * (float)L_);
  for (int l = (int)threadIdx.x; l < L_; l += 1024)
    mv[(size_t)b * L_ + l] = re[l] * scale;
}

// ------------------------------------------------------------------
// topk: 1024 threads, shuffle-reduce argmax x7, then softmax.
// ------------------------------------------------------------------
__global__ __launch_bounds__(1024) void topk_kernel(
    const float* __restrict__ mv, int* __restrict__ idx, float* __restrict__ wts)
{
  __shared__ float vals[L_];
  __shared__ float wm[16];
  __shared__ int wi[16];
  __shared__ int chosen[TOPK];
  const int t = (int)threadIdx.x;
  const int lane = t & 63, wv = t >> 6;
  float s0 = 0.f, s1 = 0.f;
#pragma unroll
  for (int b = 0; b < B_; ++b) {
    s0 += mv[(size_t)b * L_ + t];
    s1 += mv[(size_t)b * L_ + t + 1024];
  }
  vals[t] = s0; vals[t + 1024] = s1;
  __syncthreads();
  for (int kk = 0; kk < TOPK; ++kk) {
    float v0 = vals[t]; int i0 = t;
    const float v1 = vals[t + 1024];
    if (v1 > v0) { v0 = v1; i0 = t + 1024; }
#pragma unroll
    for (int off = 32; off; off >>= 1) {
      const float ov = __shfl_xor(v0, off, 64);
      const int oi = __shfl_xor(i0, off, 64);
      if (ov > v0 || (ov == v0 && oi < i0)) { v0 = ov; i0 = oi; }
    }
    if (lane == 0) { wm[wv] = v0; wi[wv] = i0; }
    __syncthreads();
    if (t == 0) {
      float m = wm[0]; int mi = wi[0];
      for (int i2 = 1; i2 < 16; ++i2)
        if (wm[i2] > m || (wm[i2] == m && wi[i2] < mi)) { m = wm[i2]; mi = wi[i2]; }
      chosen[kk] = mi; idx[kk] = mi; vals[mi] = -1e30f;
    }
    __syncthreads();
  }
  if (t < B_) {
    float w[TOPK];
    float mx = -1e30f;
#pragma unroll
    for (int kk = 0; kk < TOPK; ++kk) {
      w[kk] = mv[(size_t)t * L_ + chosen[kk]];
      mx = fmaxf(mx, w[kk]);
    }
    float sum = 0.f;
#pragma unroll
    for (int kk = 0; kk < TOPK; ++kk) { w[kk] = __expf(w[kk] - mx); sum += w[kk]; }
    const float inv = 1.0f / sum;
#pragma unroll
    for (int kk = 0; kk < TOPK; ++kk) wts[t * TOPK + kk] = w[kk] * inv;
  }
}

// ------------------------------------------------------------------
// context: 4 waves/block, one output row per wave, half8 lanes,
// XCD-swizzled (contiguous l-range per XCD).
// ------------------------------------------------------------------
__global__ __launch_bounds__(256) void context_kernel(
    const _Float16* __restrict__ v, const int* __restrict__ idx,
    const float* __restrict__ wts, _Float16* __restrict__ ctx)
{
  const int raw = (int)blockIdx.x;            // 4096
  const int wg = (raw & 7) * 512 + (raw >> 3);
  const int b = wg >> 9;                      // 512 blocks per batch
  const int l = ((wg & 511) << 2) + ((int)threadIdx.x >> 6);
  const int lane = (int)threadIdx.x & 63;
  float acc[8] = {};
#pragma unroll
  for (int kk = 0; kk < TOPK; ++kk) {
    const float w = wts[b * TOPK + kk];
    const int src = (l + idx[kk]) & (L_ - 1);
    const half8 x = *reinterpret_cast<const half8*>(v + ((size_t)(b << LOG2L) + src) * D_ + lane * 8);
#pragma unroll
    for (int j = 0; j < 8; ++j) acc[j] = fmaf(w, (float)x[j], acc[j]);
  }
  half8 o;
#pragma unroll
  for (int j = 0; j < 8; ++j) o[j] = (_Float16)acc[j];
  *reinterpret_cast<half8*>(ctx + ((size_t)(b << LOG2L) + l) * D_ + lane * 8) = o;
}

// ------------------------------------------------------------------
extern "C" void kernel_launch(void* const* d_in, const int* in_sizes, int n_in,
                              void* d_out, int out_size, void* d_ws, size_t ws_size,
                              hipStream_t stream)
{
  (void)in_sizes; (void)n_in; (void)out_size; (void)ws_size;
  const float* Q   = (const float*)d_in[0];
  const float* K   = (const float*)d_in[1];
  const float* V   = (const float*)d_in[2];
  const float* WQ  = (const float*)d_in[3];
  const float* WK  = (const float*)d_in[4];
  const float* WV  = (const float*)d_in[5];
  const float* Wfc = (const float*)d_in[6];
  float* out = (float*)d_out;

  char* ws = (char*)d_ws;
  const size_t sz_h   = (size_t)M_ * D_ * sizeof(_Float16);    // 16.78 MB
  const size_t sz_w16 = (size_t)D_ * D_ * sizeof(_Float16);    // 512 KB
  _Float16*  qT16  = (_Float16*)(ws);
  _Float16*  kT16  = (_Float16*)(ws + sz_h);
  _Float16*  vs16  = (_Float16*)(ws + 2 * sz_h);
  _Float16*  ctx16 = (_Float16*)(ws + 3 * sz_h);
  _Float16*  WQt   = (_Float16*)(ws + 4 * sz_h);
  _Float16*  WKt   = (_Float16*)(ws + 4 * sz_h + sz_w16);
  _Float16*  WVt   = (_Float16*)(ws + 4 * sz_h + 2 * sz_w16);
  _Float16*  Wfct  = (_Float16*)(ws + 4 * sz_h + 3 * sz_w16);
  float*     S     = (float*)(ws + 4 * sz_h + 4 * sz_w16);
  float*     mv    = (float*)((char*)S + (size_t)B_ * L_ * 2 * sizeof(float));
  int*       idx   = (int*)((char*)mv + (size_t)B_ * L_ * sizeof(float));
  float*     wts   = (float*)((char*)idx + 64);

  convw_kernel<<<256, 256, 0, stream>>>(WQ, WK, WV, Wfc, WQt, WKt, WVt, Wfct);
  hipMemsetAsync(S, 0, (size_t)B_ * L_ * 2 * sizeof(float), stream);

  gemm_f16_kernel<0, 3><<<NWG, 256, 0, stream>>>(Q, nullptr, WQt, nullptr, qT16);
  gemm_f16_kernel<0, 3><<<NWG, 256, 0, stream>>>(K, nullptr, WKt, nullptr, kT16);

  corr_fft_kernel<<<B_ * (D_ / (2 * NSEQ)), 512, 0, stream>>>(qT16, kT16, S);
  ifft_kernel<<<B_, 1024, 0, stream>>>(S, mv);
  topk_kernel<<<1, 1024, 0, stream>>>(mv, idx, wts);

  gemm_f16_kernel<0, 2><<<NWG, 256, 0, stream>>>(V, nullptr, WVt, nullptr, vs16);
  context_kernel<<<4096, 256, 0, stream>>>(vs16, idx, wts, ctx16);
  gemm_f16_kernel<1, 0><<<NWG, 256, 0, stream>>>(nullptr, ctx16, Wfct, out, nullptr);
}

// Round 11
// 173.878 us; speedup vs baseline: 1.1359x; 1.1359x over previous
//
#include <hip/hip_runtime.h>
#include <math.h>

#define B_ 8
#define L_ 2048
#define D_ 512
#define LOG2L 11
#define TOPK 7
#define M_ (B_ * L_)     // 16384

typedef __attribute__((ext_vector_type(8))) _Float16 half8;
typedef __attribute__((ext_vector_type(4))) _Float16 half4;
typedef __attribute__((ext_vector_type(4))) float f32x4;

// ------------------------------------------------------------------
// convw: 4 weight mats fp32 [512][512] (k-major) -> f16 [n][k].
// ------------------------------------------------------------------
__global__ __launch_bounds__(256) void convw_kernel(
    const float* __restrict__ W0, const float* __restrict__ W1,
    const float* __restrict__ W2, const float* __restrict__ W3,
    _Float16* __restrict__ T0, _Float16* __restrict__ T1,
    _Float16* __restrict__ T2, _Float16* __restrict__ T3)
{
  __shared__ float tile[64][65];
  const int t = (int)threadIdx.x;
  const int mat = (int)blockIdx.x >> 6;
  const int tb = (int)blockIdx.x & 63;
  const float* W = (mat == 0) ? W0 : (mat == 1) ? W1 : (mat == 2) ? W2 : W3;
  _Float16* Wt = (mat == 0) ? T0 : (mat == 1) ? T1 : (mat == 2) ? T2 : T3;
  const int k0 = (tb >> 3) * 64;
  const int n0 = (tb & 7) * 64;
#pragma unroll
  for (int i = 0; i < 4; ++i) {
    const int kl = (t >> 4) + i * 16;
    const float4 v = *reinterpret_cast<const float4*>(&W[(size_t)(k0 + kl) * D_ + n0 + (t & 15) * 4]);
    tile[kl][(t & 15) * 4 + 0] = v.x;
    tile[kl][(t & 15) * 4 + 1] = v.y;
    tile[kl][(t & 15) * 4 + 2] = v.z;
    tile[kl][(t & 15) * 4 + 3] = v.w;
  }
  __syncthreads();
  const int nl = t >> 2, q = t & 3;
  half8 h0, h1;
#pragma unroll
  for (int j = 0; j < 8; ++j) {
    h0[j] = (_Float16)tile[q * 16 + j][nl];
    h1[j] = (_Float16)tile[q * 16 + 8 + j][nl];
  }
  _Float16* dst = &Wt[(size_t)(n0 + nl) * D_ + k0 + q * 16];
  *reinterpret_cast<half8*>(dst) = h0;
  *reinterpret_cast<half8*>(dst + 8) = h1;
}

// ------------------------------------------------------------------
// MFMA f16 GEMM: C = A[M,512] @ W using Wt[n][k] f16.
// 64x128 tile, BK=64 (8 K-iters, halved barriers), 4 waves (2x2:
// wave tile 32x64), grid 1024 (4/CU), XCD-swizzled.
// OUTMODE: 0 = fp32 [M,512]; 2 = f16 [M,512]; 3 = f16 transposed
// [512][M] (acc reg idx is m -> half4 store).
// ------------------------------------------------------------------
#define LDSTR 72
#define NWG 1024

template <int INBF, int OUTMODE>
__global__ __launch_bounds__(256) void gemm_f16_kernel(
    const float* __restrict__ Af, const _Float16* __restrict__ Ah,
    const _Float16* __restrict__ Wt,
    float* __restrict__ Cf, _Float16* __restrict__ Ch)
{
  __shared__ __align__(16) _Float16 sA[64 * LDSTR];
  __shared__ __align__(16) _Float16 sB[128 * LDSTR];

  const int bid = (int)blockIdx.x;
  const int wg = (bid & 7) * (NWG >> 3) + (bid >> 3);
  const int m0 = (wg >> 2) << 6;        // 256 m-panels of 64
  const int n0 = (wg & 3) << 7;         // 4 n-panels of 128

  const int tid = (int)threadIdx.x;
  const int lane = tid & 63, wave = tid >> 6;
  const int wr = (wave >> 1) << 5;      // 0 / 32
  const int wc = (wave & 1) << 6;       // 0 / 64

  const int arow = tid >> 2;            // 0..63  (A stage row)
  const int ac0 = (tid & 3) << 4;       // 0,16,32,48
  const int brow = tid >> 1;            // 0..127 (B stage row)
  const int bc0 = (tid & 1) << 5;       // 0 / 32

  f32x4 acc[2][4];
  const f32x4 zero = {0.f, 0.f, 0.f, 0.f};
#pragma unroll
  for (int i = 0; i < 2; ++i)
#pragma unroll
    for (int j = 0; j < 4; ++j) acc[i][j] = zero;

  const int fr = lane & 15;
  const int g8 = (lane >> 4) << 3;

  for (int k0 = 0; k0 < D_; k0 += 64) {
    half8 ha0, ha1, hb0, hb1, hb2, hb3;
    if constexpr (INBF == 0) {
      const float* ap = Af + (size_t)(m0 + arow) * D_ + k0 + ac0;
      float tmp[16];
#pragma unroll
      for (int j = 0; j < 4; ++j) {
        const float4 v = *reinterpret_cast<const float4*>(ap + j * 4);
        tmp[j * 4 + 0] = v.x; tmp[j * 4 + 1] = v.y;
        tmp[j * 4 + 2] = v.z; tmp[j * 4 + 3] = v.w;
      }
#pragma unroll
      for (int j = 0; j < 8; ++j) { ha0[j] = (_Float16)tmp[j]; ha1[j] = (_Float16)tmp[8 + j]; }
    } else {
      const _Float16* ap = Ah + (size_t)(m0 + arow) * D_ + k0 + ac0;
      ha0 = *reinterpret_cast<const half8*>(ap);
      ha1 = *reinterpret_cast<const half8*>(ap + 8);
    }
    {
      const _Float16* bp = Wt + (size_t)(n0 + brow) * D_ + k0 + bc0;
      hb0 = *reinterpret_cast<const half8*>(bp);
      hb1 = *reinterpret_cast<const half8*>(bp + 8);
      hb2 = *reinterpret_cast<const half8*>(bp + 16);
      hb3 = *reinterpret_cast<const half8*>(bp + 24);
    }

    __syncthreads();    // previous iteration's fragment reads done
    *reinterpret_cast<half8*>(&sA[arow * LDSTR + ac0]) = ha0;
    *reinterpret_cast<half8*>(&sA[arow * LDSTR + ac0 + 8]) = ha1;
    *reinterpret_cast<half8*>(&sB[brow * LDSTR + bc0]) = hb0;
    *reinterpret_cast<half8*>(&sB[brow * LDSTR + bc0 + 8]) = hb1;
    *reinterpret_cast<half8*>(&sB[brow * LDSTR + bc0 + 16]) = hb2;
    *reinterpret_cast<half8*>(&sB[brow * LDSTR + bc0 + 24]) = hb3;
    __syncthreads();

#pragma unroll
    for (int ks = 0; ks < 64; ks += 32) {
      half8 afr[2], bfr[4];
#pragma unroll
      for (int i = 0; i < 2; ++i)
        afr[i] = *reinterpret_cast<const half8*>(&sA[(wr + i * 16 + fr) * LDSTR + ks + g8]);
#pragma unroll
      for (int i = 0; i < 4; ++i)
        bfr[i] = *reinterpret_cast<const half8*>(&sB[(wc + i * 16 + fr) * LDSTR + ks + g8]);
#pragma unroll
      for (int mi = 0; mi < 2; ++mi)
#pragma unroll
        for (int ni = 0; ni < 4; ++ni)
          acc[mi][ni] = __builtin_amdgcn_mfma_f32_16x16x32_f16(afr[mi], bfr[ni], acc[mi][ni], 0, 0, 0);
    }
  }

  const int orow = (lane >> 4) << 2;   // m sub-offset (reg idx r adds 0..3)
  const int ocol = lane & 15;          // n sub-offset
  if constexpr (OUTMODE == 0) {
#pragma unroll
    for (int mi = 0; mi < 2; ++mi)
#pragma unroll
      for (int ni = 0; ni < 4; ++ni)
#pragma unroll
        for (int r = 0; r < 4; ++r)
          Cf[(size_t)(m0 + wr + mi * 16 + orow + r) * D_ + n0 + wc + ni * 16 + ocol] = acc[mi][ni][r];
  } else if constexpr (OUTMODE == 2) {
#pragma unroll
    for (int mi = 0; mi < 2; ++mi)
#pragma unroll
      for (int ni = 0; ni < 4; ++ni)
#pragma unroll
        for (int r = 0; r < 4; ++r)
          Ch[(size_t)(m0 + wr + mi * 16 + orow + r) * D_ + n0 + wc + ni * 16 + ocol] = (_Float16)acc[mi][ni][r];
  } else {
    // CT[n][m] f16: acc[mi][ni] holds 4 consecutive m -> half4 store
#pragma unroll
    for (int ni = 0; ni < 4; ++ni) {
      const size_t nrow = (size_t)(n0 + wc + ni * 16 + ocol) * M_;
#pragma unroll
      for (int mi = 0; mi < 2; ++mi) {
        half4 hv;
        hv[0] = (_Float16)acc[mi][ni][0]; hv[1] = (_Float16)acc[mi][ni][1];
        hv[2] = (_Float16)acc[mi][ni][2]; hv[3] = (_Float16)acc[mi][ni][3];
        *reinterpret_cast<half4*>(&Ch[nrow + m0 + wr + mi * 16 + orow]) = hv;
      }
    }
  }
}

// ------------------------------------------------------------------
// corr_fft v6: R9 structure (256 thr, DCHUNK=4) + DOUBLE-BUFFERED
// LDS exchanges: each phase writes the other buffer, so only ONE
// barrier per phase (4/d-iter instead of 8). Hermitian-half atomics.
// ------------------------------------------------------------------
__device__ __forceinline__ int rev11(int x) {
  return (int)(__brev((unsigned)x) >> (32 - LOG2L));
}

#define DCHUNK 4
#define PADI(i) ((i) + ((i) >> 5))

#define BFLY(j0, j1, wr_, wi_) { \
  const float ar = xr[j0], ai = xi[j0], br = xr[j1], bi = xi[j1]; \
  xr[j0] = ar + br; xi[j0] = ai + bi; \
  const float tr = ar - br, ti = ai - bi; \
  xr[j1] = tr * (wr_) - ti * (wi_); \
  xi[j1] = tr * (wi_) + ti * (wr_); }

__global__ __launch_bounds__(256) void corr_fft_kernel(
    const _Float16* __restrict__ qT, const _Float16* __restrict__ kT,
    float* __restrict__ S)
{
  __shared__ float re0[2112], im0[2112];
  __shared__ float re1[2112], im1[2112];
  const int t = (int)threadIdx.x;
  const int blk = (int)blockIdx.x;
  const int b = blk >> 7;                   // 128 chunks per batch
  const int d0 = (blk & 127) * DCHUNK;
  const int u2 = t & 31, u3 = t & 3;

  float w2048r, w2048i, w256r, w256i, w32r, w32i;
  {
    float s_, c_;
    __sincosf(-6.283185307179586f * (float)t / 2048.f, &s_, &c_);
    w2048r = c_; w2048i = s_;
    __sincosf(-6.283185307179586f * (float)u2 / 256.f, &s_, &c_);
    w256r = c_; w256i = s_;
    __sincosf(-6.283185307179586f * (float)u3 / 32.f, &s_, &c_);
    w32r = c_; w32i = s_;
  }
  const float w1024r = w2048r * w2048r - w2048i * w2048i, w1024i = 2.f * w2048r * w2048i;
  const float w512r  = w1024r * w1024r - w1024i * w1024i, w512i  = 2.f * w1024r * w1024i;
  const float w128r  = w256r * w256r - w256i * w256i,     w128i  = 2.f * w256r * w256i;
  const float w64r   = w128r * w128r - w128i * w128i,     w64i   = 2.f * w128r * w128i;
  const float w16r   = w32r * w32r - w32i * w32i,         w16i   = 2.f * w32r * w32i;
  const float w8r    = w16r * w16r - w16i * w16i,         w8i    = 2.f * w16r * w16i;

  const float C_ = 0.70710678118654752f;
  const float W8R[4] = {1.f, C_, 0.f, -C_};
  const float W8I[4] = {0.f, -C_, -1.f, -C_};

  float pr[8] = {}, pi_[8] = {};

  for (int dc = 0; dc < DCHUNK; ++dc) {
    const int d = d0 + dc;
    const _Float16* qrow = qT + (size_t)d * M_ + (size_t)b * L_;
    const _Float16* krow = kT + (size_t)d * M_ + (size_t)b * L_;

    float xr[8], xi[8];
#pragma unroll
    for (int j = 0; j < 8; ++j) {
      xr[j] = (float)qrow[t + 256 * j];
      xi[j] = (float)krow[t + 256 * j];
    }

    // ---- round 1: stages half=1024,512,256
#pragma unroll
    for (int j = 0; j < 4; ++j) {
      const float wr_ = w2048r * W8R[j] - w2048i * W8I[j];
      const float wi_ = w2048r * W8I[j] + w2048i * W8R[j];
      BFLY(j, j + 4, wr_, wi_);
    }
#pragma unroll
    for (int base = 0; base < 8; base += 4) {
      BFLY(base + 0, base + 2, w1024r, w1024i);
      BFLY(base + 1, base + 3, w1024i, -w1024r);
    }
#pragma unroll
    for (int a = 0; a < 8; a += 2) BFLY(a, a + 1, w512r, w512i);

    // ---- exchange 1 (buf0): pos t+256j -> (t>>5)*256 + (t&31) + 32j
#pragma unroll
    for (int j = 0; j < 8; ++j) {
      const int p = t + 256 * j;
      re0[PADI(p)] = xr[j]; im0[PADI(p)] = xi[j];
    }
    __syncthreads();
#pragma unroll
    for (int j = 0; j < 8; ++j) {
      const int p = ((t >> 5) << 8) + u2 + 32 * j;
      xr[j] = re0[PADI(p)]; xi[j] = im0[PADI(p)];
    }

    // ---- round 2: stages half=128,64,32
#pragma unroll
    for (int j = 0; j < 4; ++j) {
      const float wr_ = w256r * W8R[j] - w256i * W8I[j];
      const float wi_ = w256r * W8I[j] + w256i * W8R[j];
      BFLY(j, j + 4, wr_, wi_);
    }
#pragma unroll
    for (int base = 0; base < 8; base += 4) {
      BFLY(base + 0, base + 2, w128r, w128i);
      BFLY(base + 1, base + 3, w128i, -w128r);
    }
#pragma unroll
    for (int a = 0; a < 8; a += 2) BFLY(a, a + 1, w64r, w64i);

    // ---- exchange 2 (buf1) -> (t>>2)*32 + (t&3) + 4j
#pragma unroll
    for (int j = 0; j < 8; ++j) {
      const int p = ((t >> 5) << 8) + u2 + 32 * j;
      re1[PADI(p)] = xr[j]; im1[PADI(p)] = xi[j];
    }
    __syncthreads();
#pragma unroll
    for (int j = 0; j < 8; ++j) {
      const int p = ((t >> 2) << 5) + u3 + 4 * j;
      xr[j] = re1[PADI(p)]; xi[j] = im1[PADI(p)];
    }

    // ---- round 3: stages half=16,8,4
#pragma unroll
    for (int j = 0; j < 4; ++j) {
      const float wr_ = w32r * W8R[j] - w32i * W8I[j];
      const float wi_ = w32r * W8I[j] + w32i * W8R[j];
      BFLY(j, j + 4, wr_, wi_);
    }
#pragma unroll
    for (int base = 0; base < 8; base += 4) {
      BFLY(base + 0, base + 2, w16r, w16i);
      BFLY(base + 1, base + 3, w16i, -w16r);
    }
#pragma unroll
    for (int a = 0; a < 8; a += 2) BFLY(a, a + 1, w8r, w8i);

    // ---- exchange 3 (buf0) -> pos 8t+j
#pragma unroll
    for (int j = 0; j < 8; ++j) {
      const int p = ((t >> 2) << 5) + u3 + 4 * j;
      re0[PADI(p)] = xr[j]; im0[PADI(p)] = xi[j];
    }
    __syncthreads();
#pragma unroll
    for (int j = 0; j < 8; ++j) {
      const int p = 8 * t + j;
      xr[j] = re0[PADI(p)]; xi[j] = im0[PADI(p)];
    }

    // ---- round 4: stages half=2,1
#pragma unroll
    for (int base = 0; base < 8; base += 4) {
      BFLY(base + 0, base + 2, 1.f, 0.f);
      BFLY(base + 1, base + 3, 0.f, -1.f);
    }
#pragma unroll
    for (int a = 0; a < 8; a += 2) BFLY(a, a + 1, 1.f, 0.f);

    // ---- final write (buf1), then Hermitian split
#pragma unroll
    for (int j = 0; j < 8; ++j) {
      const int p = 8 * t + j;
      re1[PADI(p)] = xr[j]; im1[PADI(p)] = xi[j];
    }
    __syncthreads();

    // ---- Hermitian split + product (pos p holds freq rev11(p))
#pragma unroll
    for (int i = 0; i < 8; ++i) {
      const int p = t + 256 * i;
      const int f = rev11(p);
      const int fm = (L_ - f) & (L_ - 1);
      const int pm = rev11(fm);
      const float Ar = re1[PADI(p)],  Ai = im1[PADI(p)];
      const float Br = re1[PADI(pm)], Bi = -im1[PADI(pm)];
      const float Qr = 0.5f * (Ar + Br), Qi = 0.5f * (Ai + Bi);
      const float Cr = 0.5f * (Ai - Bi), Ci = 0.5f * (Ar - Br);
      pr[i]  += Qr * Cr - Qi * Ci;
      pi_[i] += Qr * Ci + Qi * Cr;
    }
    // no bottom barrier: next iter's first write targets buf0, whose
    // last readers (exchange 3) finished before the barrier above.
  }

  // only the non-redundant half: P[L-f] = conj(P[f])
#pragma unroll
  for (int i = 0; i < 8; ++i) {
    const int p = t + 256 * i;
    const int f = rev11(p);
    if (f <= L_ / 2) {
      atomicAdd(&S[((size_t)b * L_ + p) * 2 + 0], pr[i]);
      atomicAdd(&S[((size_t)b * L_ + p) * 2 + 1], pi_[i]);
    }
  }
}

// ------------------------------------------------------------------
// Inverse DIT (bit-rev in, natural out), per b, 1024 threads.
// ------------------------------------------------------------------
__global__ __launch_bounds__(1024) void ifft_kernel(
    const float* __restrict__ S, float* __restrict__ mv)
{
  __shared__ float re[L_];
  __shared__ float im[L_];
  const int b = blockIdx.x;
  for (int p = (int)threadIdx.x; p < L_; p += 1024) {
    const int f = rev11(p);
    float sr, si;
    if (f <= L_ / 2) {
      sr = S[((size_t)b * L_ + p) * 2 + 0];
      si = S[((size_t)b * L_ + p) * 2 + 1];
    } else {
      const int pm = rev11(L_ - f);
      sr = S[((size_t)b * L_ + pm) * 2 + 0];
      si = -S[((size_t)b * L_ + pm) * 2 + 1];
    }
    re[p] = sr; im[p] = si;
  }
  __syncthreads();
  for (int s = 1; s <= LOG2L; ++s) {
    const int half = 1 << (s - 1);
    {
      const int j = (int)threadIdx.x;
      const int pos = j & (half - 1);
      const int i0 = ((j >> (s - 1)) << s) + pos;
      const int i1 = i0 + half;
      const float ang = 3.14159265358979323846f * (float)pos / (float)half;
      float wi, wr;
      __sincosf(ang, &wi, &wr);
      const float br = re[i1], bi = im[i1];
      const float tr = br * wr - bi * wi;
      const float ti = br * wi + bi * wr;
      const float ar = re[i0], ai = im[i0];
      re[i0] = ar + tr; im[i0] = ai + ti;
      re[i1] = ar - tr; im[i1] = ai - ti;
    }
    __syncthreads();
  }
  const float scale = 1.0f / ((float)D_ * (float)L_);
  for (int l = (int)threadIdx.x; l < L_; l += 1024)
    mv[(size_t)b * L_ + l] = re[l] * scale;
}

// ------------------------------------------------------------------
// topk: 1024 threads, shuffle-reduce argmax x7, then softmax.
// ------------------------------------------------------------------
__global__ __launch_bounds__(1024) void topk_kernel(
    const float* __restrict__ mv, int* __restrict__ idx, float* __restrict__ wts)
{
  __shared__ float vals[L_];
  __shared__ float wm[16];
  __shared__ int wi[16];
  __shared__ int chosen[TOPK];
  const int t = (int)threadIdx.x;
  const int lane = t & 63, wv = t >> 6;
  float s0 = 0.f, s1 = 0.f;
#pragma unroll
  for (int b = 0; b < B_; ++b) {
    s0 += mv[(size_t)b * L_ + t];
    s1 += mv[(size_t)b * L_ + t + 1024];
  }
  vals[t] = s0; vals[t + 1024] = s1;
  __syncthreads();
  for (int kk = 0; kk < TOPK; ++kk) {
    float v0 = vals[t]; int i0 = t;
    const float v1 = vals[t + 1024];
    if (v1 > v0) { v0 = v1; i0 = t + 1024; }
#pragma unroll
    for (int off = 32; off; off >>= 1) {
      const float ov = __shfl_xor(v0, off, 64);
      const int oi = __shfl_xor(i0, off, 64);
      if (ov > v0 || (ov == v0 && oi < i0)) { v0 = ov; i0 = oi; }
    }
    if (lane == 0) { wm[wv] = v0; wi[wv] = i0; }
    __syncthreads();
    if (t == 0) {
      float m = wm[0]; int mi = wi[0];
      for (int i2 = 1; i2 < 16; ++i2)
        if (wm[i2] > m || (wm[i2] == m && wi[i2] < mi)) { m = wm[i2]; mi = wi[i2]; }
      chosen[kk] = mi; idx[kk] = mi; vals[mi] = -1e30f;
    }
    __syncthreads();
  }
  if (t < B_) {
    float w[TOPK];
    float mx = -1e30f;
#pragma unroll
    for (int kk = 0; kk < TOPK; ++kk) {
      w[kk] = mv[(size_t)t * L_ + chosen[kk]];
      mx = fmaxf(mx, w[kk]);
    }
    float sum = 0.f;
#pragma unroll
    for (int kk = 0; kk < TOPK; ++kk) { w[kk] = __expf(w[kk] - mx); sum += w[kk]; }
    const float inv = 1.0f / sum;
#pragma unroll
    for (int kk = 0; kk < TOPK; ++kk) wts[t * TOPK + kk] = w[kk] * inv;
  }
}

// ------------------------------------------------------------------
// context: 4 waves/block, one output row per wave, half8 lanes,
// XCD-swizzled (contiguous l-range per XCD).
// ------------------------------------------------------------------
__global__ __launch_bounds__(256) void context_kernel(
    const _Float16* __restrict__ v, const int* __restrict__ idx,
    const float* __restrict__ wts, _Float16* __restrict__ ctx)
{
  const int raw = (int)blockIdx.x;            // 4096
  const int wg = (raw & 7) * 512 + (raw >> 3);
  const int b = wg >> 9;                      // 512 blocks per batch
  const int l = ((wg & 511) << 2) + ((int)threadIdx.x >> 6);
  const int lane = (int)threadIdx.x & 63;
  float acc[8] = {};
#pragma unroll
  for (int kk = 0; kk < TOPK; ++kk) {
    const float w = wts[b * TOPK + kk];
    const int src = (l + idx[kk]) & (L_ - 1);
    const half8 x = *reinterpret_cast<const half8*>(v + ((size_t)(b << LOG2L) + src) * D_ + lane * 8);
#pragma unroll
    for (int j = 0; j < 8; ++j) acc[j] = fmaf(w, (float)x[j], acc[j]);
  }
  half8 o;
#pragma unroll
  for (int j = 0; j < 8; ++j) o[j] = (_Float16)acc[j];
  *reinterpret_cast<half8*>(ctx + ((size_t)(b << LOG2L) + l) * D_ + lane * 8) = o;
}

// ------------------------------------------------------------------
extern "C" void kernel_launch(void* const* d_in, const int* in_sizes, int n_in,
                              void* d_out, int out_size, void* d_ws, size_t ws_size,
                              hipStream_t stream)
{
  (void)in_sizes; (void)n_in; (void)out_size; (void)ws_size;
  const float* Q   = (const float*)d_in[0];
  const float* K   = (const float*)d_in[1];
  const float* V   = (const float*)d_in[2];
  const float* WQ  = (const float*)d_in[3];
  const float* WK  = (const float*)d_in[4];
  const float* WV  = (const float*)d_in[5];
  const float* Wfc = (const float*)d_in[6];
  float* out = (float*)d_out;

  char* ws = (char*)d_ws;
  const size_t sz_h   = (size_t)M_ * D_ * sizeof(_Float16);    // 16.78 MB
  const size_t sz_w16 = (size_t)D_ * D_ * sizeof(_Float16);    // 512 KB
  _Float16*  qT16  = (_Float16*)(ws);
  _Float16*  kT16  = (_Float16*)(ws + sz_h);
  _Float16*  vs16  = (_Float16*)(ws + 2 * sz_h);
  _Float16*  ctx16 = (_Float16*)(ws + 3 * sz_h);
  _Float16*  WQt   = (_Float16*)(ws + 4 * sz_h);
  _Float16*  WKt   = (_Float16*)(ws + 4 * sz_h + sz_w16);
  _Float16*  WVt   = (_Float16*)(ws + 4 * sz_h + 2 * sz_w16);
  _Float16*  Wfct  = (_Float16*)(ws + 4 * sz_h + 3 * sz_w16);
  float*     S     = (float*)(ws + 4 * sz_h + 4 * sz_w16);
  float*     mv    = (float*)((char*)S + (size_t)B_ * L_ * 2 * sizeof(float));
  int*       idx   = (int*)((char*)mv + (size_t)B_ * L_ * sizeof(float));
  float*     wts   = (float*)((char*)idx + 64);

  convw_kernel<<<256, 256, 0, stream>>>(WQ, WK, WV, Wfc, WQt, WKt, WVt, Wfct);
  hipMemsetAsync(S, 0, (size_t)B_ * L_ * 2 * sizeof(float), stream);

  gemm_f16_kernel<0, 3><<<NWG, 256, 0, stream>>>(Q, nullptr, WQt, nullptr, qT16);
  gemm_f16_kernel<0, 3><<<NWG, 256, 0, stream>>>(K, nullptr, WKt, nullptr, kT16);

  corr_fft_kernel<<<B_ * (D_ / DCHUNK), 256, 0, stream>>>(qT16, kT16, S);
  ifft_kernel<<<B_, 1024, 0, stream>>>(S, mv);
  topk_kernel<<<1, 1024, 0, stream>>>(mv, idx, wts);

  gemm_f16_kernel<0, 2><<<NWG, 256, 0, stream>>>(V, nullptr, WVt, nullptr, vs16);
  context_kernel<<<4096, 256, 0, stream>>>(vs16, idx, wts, ctx16);
  gemm_f16_kernel<1, 0><<<NWG, 256, 0, stream>>>(nullptr, ctx16, Wfct, out, nullptr);
}

// Round 12
// 166.328 us; speedup vs baseline: 1.1875x; 1.0454x over previous
//
#include <hip/hip_runtime.h>
#include <math.h>

#define B_ 8
#define L_ 2048
#define D_ 512
#define LOG2L 11
#define TOPK 7
#define M_ (B_ * L_)     // 16384

typedef __attribute__((ext_vector_type(8))) _Float16 half8;
typedef __attribute__((ext_vector_type(4))) _Float16 half4;
typedef __attribute__((ext_vector_type(4))) float f32x4;

// ------------------------------------------------------------------
// convw: 4 weight mats fp32 [512][512] (k-major) -> f16 [n][k].
// ------------------------------------------------------------------
__global__ __launch_bounds__(256) void convw_kernel(
    const float* __restrict__ W0, const float* __restrict__ W1,
    const float* __restrict__ W2, const float* __restrict__ W3,
    _Float16* __restrict__ T0, _Float16* __restrict__ T1,
    _Float16* __restrict__ T2, _Float16* __restrict__ T3)
{
  __shared__ float tile[64][65];
  const int t = (int)threadIdx.x;
  const int mat = (int)blockIdx.x >> 6;
  const int tb = (int)blockIdx.x & 63;
  const float* W = (mat == 0) ? W0 : (mat == 1) ? W1 : (mat == 2) ? W2 : W3;
  _Float16* Wt = (mat == 0) ? T0 : (mat == 1) ? T1 : (mat == 2) ? T2 : T3;
  const int k0 = (tb >> 3) * 64;
  const int n0 = (tb & 7) * 64;
#pragma unroll
  for (int i = 0; i < 4; ++i) {
    const int kl = (t >> 4) + i * 16;
    const float4 v = *reinterpret_cast<const float4*>(&W[(size_t)(k0 + kl) * D_ + n0 + (t & 15) * 4]);
    tile[kl][(t & 15) * 4 + 0] = v.x;
    tile[kl][(t & 15) * 4 + 1] = v.y;
    tile[kl][(t & 15) * 4 + 2] = v.z;
    tile[kl][(t & 15) * 4 + 3] = v.w;
  }
  __syncthreads();
  const int nl = t >> 2, q = t & 3;
  half8 h0, h1;
#pragma unroll
  for (int j = 0; j < 8; ++j) {
    h0[j] = (_Float16)tile[q * 16 + j][nl];
    h1[j] = (_Float16)tile[q * 16 + 8 + j][nl];
  }
  _Float16* dst = &Wt[(size_t)(n0 + nl) * D_ + k0 + q * 16];
  *reinterpret_cast<half8*>(dst) = h0;
  *reinterpret_cast<half8*>(dst + 8) = h1;
}

// ------------------------------------------------------------------
// MFMA f16 GEMM: C = A[M,512] @ W using Wt[n][k] f16.
// 64x128 tile, BK=64, 4 waves (2x2: wave tile 32x64), grid 1024
// (4/CU), XCD-swizzled. OUTMODE: 0 = fp32 [M,512]; 2 = f16 [M,512];
// 3 = f16 transposed [512][M] (acc reg idx is m -> half4 store).
// ------------------------------------------------------------------
#define LDSTR 72
#define NWG 1024

template <int INBF, int OUTMODE>
__global__ __launch_bounds__(256) void gemm_f16_kernel(
    const float* __restrict__ Af, const _Float16* __restrict__ Ah,
    const _Float16* __restrict__ Wt,
    float* __restrict__ Cf, _Float16* __restrict__ Ch)
{
  __shared__ __align__(16) _Float16 sA[64 * LDSTR];
  __shared__ __align__(16) _Float16 sB[128 * LDSTR];

  const int bid = (int)blockIdx.x;
  const int wg = (bid & 7) * (NWG >> 3) + (bid >> 3);
  const int m0 = (wg >> 2) << 6;        // 256 m-panels of 64
  const int n0 = (wg & 3) << 7;         // 4 n-panels of 128

  const int tid = (int)threadIdx.x;
  const int lane = tid & 63, wave = tid >> 6;
  const int wr = (wave >> 1) << 5;      // 0 / 32
  const int wc = (wave & 1) << 6;       // 0 / 64

  const int arow = tid >> 2;            // 0..63  (A stage row)
  const int ac0 = (tid & 3) << 4;       // 0,16,32,48
  const int brow = tid >> 1;            // 0..127 (B stage row)
  const int bc0 = (tid & 1) << 5;       // 0 / 32

  f32x4 acc[2][4];
  const f32x4 zero = {0.f, 0.f, 0.f, 0.f};
#pragma unroll
  for (int i = 0; i < 2; ++i)
#pragma unroll
    for (int j = 0; j < 4; ++j) acc[i][j] = zero;

  const int fr = lane & 15;
  const int g8 = (lane >> 4) << 3;

  for (int k0 = 0; k0 < D_; k0 += 64) {
    half8 ha0, ha1, hb0, hb1, hb2, hb3;
    if constexpr (INBF == 0) {
      const float* ap = Af + (size_t)(m0 + arow) * D_ + k0 + ac0;
      float tmp[16];
#pragma unroll
      for (int j = 0; j < 4; ++j) {
        const float4 v = *reinterpret_cast<const float4*>(ap + j * 4);
        tmp[j * 4 + 0] = v.x; tmp[j * 4 + 1] = v.y;
        tmp[j * 4 + 2] = v.z; tmp[j * 4 + 3] = v.w;
      }
#pragma unroll
      for (int j = 0; j < 8; ++j) { ha0[j] = (_Float16)tmp[j]; ha1[j] = (_Float16)tmp[8 + j]; }
    } else {
      const _Float16* ap = Ah + (size_t)(m0 + arow) * D_ + k0 + ac0;
      ha0 = *reinterpret_cast<const half8*>(ap);
      ha1 = *reinterpret_cast<const half8*>(ap + 8);
    }
    {
      const _Float16* bp = Wt + (size_t)(n0 + brow) * D_ + k0 + bc0;
      hb0 = *reinterpret_cast<const half8*>(bp);
      hb1 = *reinterpret_cast<const half8*>(bp + 8);
      hb2 = *reinterpret_cast<const half8*>(bp + 16);
      hb3 = *reinterpret_cast<const half8*>(bp + 24);
    }

    __syncthreads();    // previous iteration's fragment reads done
    *reinterpret_cast<half8*>(&sA[arow * LDSTR + ac0]) = ha0;
    *reinterpret_cast<half8*>(&sA[arow * LDSTR + ac0 + 8]) = ha1;
    *reinterpret_cast<half8*>(&sB[brow * LDSTR + bc0]) = hb0;
    *reinterpret_cast<half8*>(&sB[brow * LDSTR + bc0 + 8]) = hb1;
    *reinterpret_cast<half8*>(&sB[brow * LDSTR + bc0 + 16]) = hb2;
    *reinterpret_cast<half8*>(&sB[brow * LDSTR + bc0 + 24]) = hb3;
    __syncthreads();

#pragma unroll
    for (int ks = 0; ks < 64; ks += 32) {
      half8 afr[2], bfr[4];
#pragma unroll
      for (int i = 0; i < 2; ++i)
        afr[i] = *reinterpret_cast<const half8*>(&sA[(wr + i * 16 + fr) * LDSTR + ks + g8]);
#pragma unroll
      for (int i = 0; i < 4; ++i)
        bfr[i] = *reinterpret_cast<const half8*>(&sB[(wc + i * 16 + fr) * LDSTR + ks + g8]);
#pragma unroll
      for (int mi = 0; mi < 2; ++mi)
#pragma unroll
        for (int ni = 0; ni < 4; ++ni)
          acc[mi][ni] = __builtin_amdgcn_mfma_f32_16x16x32_f16(afr[mi], bfr[ni], acc[mi][ni], 0, 0, 0);
    }
  }

  const int orow = (lane >> 4) << 2;   // m sub-offset (reg idx r adds 0..3)
  const int ocol = lane & 15;          // n sub-offset
  if constexpr (OUTMODE == 0) {
#pragma unroll
    for (int mi = 0; mi < 2; ++mi)
#pragma unroll
      for (int ni = 0; ni < 4; ++ni)
#pragma unroll
        for (int r = 0; r < 4; ++r)
          Cf[(size_t)(m0 + wr + mi * 16 + orow + r) * D_ + n0 + wc + ni * 16 + ocol] = acc[mi][ni][r];
  } else if constexpr (OUTMODE == 2) {
#pragma unroll
    for (int mi = 0; mi < 2; ++mi)
#pragma unroll
      for (int ni = 0; ni < 4; ++ni)
#pragma unroll
        for (int r = 0; r < 4; ++r)
          Ch[(size_t)(m0 + wr + mi * 16 + orow + r) * D_ + n0 + wc + ni * 16 + ocol] = (_Float16)acc[mi][ni][r];
  } else {
    // CT[n][m] f16: acc[mi][ni] holds 4 consecutive m -> half4 store
#pragma unroll
    for (int ni = 0; ni < 4; ++ni) {
      const size_t nrow = (size_t)(n0 + wc + ni * 16 + ocol) * M_;
#pragma unroll
      for (int mi = 0; mi < 2; ++mi) {
        half4 hv;
        hv[0] = (_Float16)acc[mi][ni][0]; hv[1] = (_Float16)acc[mi][ni][1];
        hv[2] = (_Float16)acc[mi][ni][2]; hv[3] = (_Float16)acc[mi][ni][3];
        *reinterpret_cast<half4*>(&Ch[nrow + m0 + wr + mi * 16 + orow]) = hv;
      }
    }
  }
}

// ------------------------------------------------------------------
// corr_fft v7: R11 double-buffered register FFT, but NO ATOMICS —
// each block stores its full spectrum product to a private slice
// Sp[blk][2048] (float2). A separate reduce kernel sums chunks.
// ------------------------------------------------------------------
__device__ __forceinline__ int rev11(int x) {
  return (int)(__brev((unsigned)x) >> (32 - LOG2L));
}

#define DCHUNK 4
#define PADI(i) ((i) + ((i) >> 5))

#define BFLY(j0, j1, wr_, wi_) { \
  const float ar = xr[j0], ai = xi[j0], br = xr[j1], bi = xi[j1]; \
  xr[j0] = ar + br; xi[j0] = ai + bi; \
  const float tr = ar - br, ti = ai - bi; \
  xr[j1] = tr * (wr_) - ti * (wi_); \
  xi[j1] = tr * (wi_) + ti * (wr_); }

__global__ __launch_bounds__(256) void corr_fft_kernel(
    const _Float16* __restrict__ qT, const _Float16* __restrict__ kT,
    float2* __restrict__ Sp)
{
  __shared__ float re0[2112], im0[2112];
  __shared__ float re1[2112], im1[2112];
  const int t = (int)threadIdx.x;
  const int blk = (int)blockIdx.x;
  const int b = blk >> 7;                   // 128 chunks per batch
  const int d0 = (blk & 127) * DCHUNK;
  const int u2 = t & 31, u3 = t & 3;

  float w2048r, w2048i, w256r, w256i, w32r, w32i;
  {
    float s_, c_;
    __sincosf(-6.283185307179586f * (float)t / 2048.f, &s_, &c_);
    w2048r = c_; w2048i = s_;
    __sincosf(-6.283185307179586f * (float)u2 / 256.f, &s_, &c_);
    w256r = c_; w256i = s_;
    __sincosf(-6.283185307179586f * (float)u3 / 32.f, &s_, &c_);
    w32r = c_; w32i = s_;
  }
  const float w1024r = w2048r * w2048r - w2048i * w2048i, w1024i = 2.f * w2048r * w2048i;
  const float w512r  = w1024r * w1024r - w1024i * w1024i, w512i  = 2.f * w1024r * w1024i;
  const float w128r  = w256r * w256r - w256i * w256i,     w128i  = 2.f * w256r * w256i;
  const float w64r   = w128r * w128r - w128i * w128i,     w64i   = 2.f * w128r * w128i;
  const float w16r   = w32r * w32r - w32i * w32i,         w16i   = 2.f * w32r * w32i;
  const float w8r    = w16r * w16r - w16i * w16i,         w8i    = 2.f * w16r * w16i;

  const float C_ = 0.70710678118654752f;
  const float W8R[4] = {1.f, C_, 0.f, -C_};
  const float W8I[4] = {0.f, -C_, -1.f, -C_};

  float pr[8] = {}, pi_[8] = {};

  for (int dc = 0; dc < DCHUNK; ++dc) {
    const int d = d0 + dc;
    const _Float16* qrow = qT + (size_t)d * M_ + (size_t)b * L_;
    const _Float16* krow = kT + (size_t)d * M_ + (size_t)b * L_;

    float xr[8], xi[8];
#pragma unroll
    for (int j = 0; j < 8; ++j) {
      xr[j] = (float)qrow[t + 256 * j];
      xi[j] = (float)krow[t + 256 * j];
    }

    // ---- round 1: stages half=1024,512,256
#pragma unroll
    for (int j = 0; j < 4; ++j) {
      const float wr_ = w2048r * W8R[j] - w2048i * W8I[j];
      const float wi_ = w2048r * W8I[j] + w2048i * W8R[j];
      BFLY(j, j + 4, wr_, wi_);
    }
#pragma unroll
    for (int base = 0; base < 8; base += 4) {
      BFLY(base + 0, base + 2, w1024r, w1024i);
      BFLY(base + 1, base + 3, w1024i, -w1024r);
    }
#pragma unroll
    for (int a = 0; a < 8; a += 2) BFLY(a, a + 1, w512r, w512i);

    // ---- exchange 1 (buf0): pos t+256j -> (t>>5)*256 + (t&31) + 32j
#pragma unroll
    for (int j = 0; j < 8; ++j) {
      const int p = t + 256 * j;
      re0[PADI(p)] = xr[j]; im0[PADI(p)] = xi[j];
    }
    __syncthreads();
#pragma unroll
    for (int j = 0; j < 8; ++j) {
      const int p = ((t >> 5) << 8) + u2 + 32 * j;
      xr[j] = re0[PADI(p)]; xi[j] = im0[PADI(p)];
    }

    // ---- round 2: stages half=128,64,32
#pragma unroll
    for (int j = 0; j < 4; ++j) {
      const float wr_ = w256r * W8R[j] - w256i * W8I[j];
      const float wi_ = w256r * W8I[j] + w256i * W8R[j];
      BFLY(j, j + 4, wr_, wi_);
    }
#pragma unroll
    for (int base = 0; base < 8; base += 4) {
      BFLY(base + 0, base + 2, w128r, w128i);
      BFLY(base + 1, base + 3, w128i, -w128r);
    }
#pragma unroll
    for (int a = 0; a < 8; a += 2) BFLY(a, a + 1, w64r, w64i);

    // ---- exchange 2 (buf1) -> (t>>2)*32 + (t&3) + 4j
#pragma unroll
    for (int j = 0; j < 8; ++j) {
      const int p = ((t >> 5) << 8) + u2 + 32 * j;
      re1[PADI(p)] = xr[j]; im1[PADI(p)] = xi[j];
    }
    __syncthreads();
#pragma unroll
    for (int j = 0; j < 8; ++j) {
      const int p = ((t >> 2) << 5) + u3 + 4 * j;
      xr[j] = re1[PADI(p)]; xi[j] = im1[PADI(p)];
    }

    // ---- round 3: stages half=16,8,4
#pragma unroll
    for (int j = 0; j < 4; ++j) {
      const float wr_ = w32r * W8R[j] - w32i * W8I[j];
      const float wi_ = w32r * W8I[j] + w32i * W8R[j];
      BFLY(j, j + 4, wr_, wi_);
    }
#pragma unroll
    for (int base = 0; base < 8; base += 4) {
      BFLY(base + 0, base + 2, w16r, w16i);
      BFLY(base + 1, base + 3, w16i, -w16r);
    }
#pragma unroll
    for (int a = 0; a < 8; a += 2) BFLY(a, a + 1, w8r, w8i);

    // ---- exchange 3 (buf0) -> pos 8t+j
#pragma unroll
    for (int j = 0; j < 8; ++j) {
      const int p = ((t >> 2) << 5) + u3 + 4 * j;
      re0[PADI(p)] = xr[j]; im0[PADI(p)] = xi[j];
    }
    __syncthreads();
#pragma unroll
    for (int j = 0; j < 8; ++j) {
      const int p = 8 * t + j;
      xr[j] = re0[PADI(p)]; xi[j] = im0[PADI(p)];
    }

    // ---- round 4: stages half=2,1
#pragma unroll
    for (int base = 0; base < 8; base += 4) {
      BFLY(base + 0, base + 2, 1.f, 0.f);
      BFLY(base + 1, base + 3, 0.f, -1.f);
    }
#pragma unroll
    for (int a = 0; a < 8; a += 2) BFLY(a, a + 1, 1.f, 0.f);

    // ---- final write (buf1), then Hermitian split
#pragma unroll
    for (int j = 0; j < 8; ++j) {
      const int p = 8 * t + j;
      re1[PADI(p)] = xr[j]; im1[PADI(p)] = xi[j];
    }
    __syncthreads();

    // ---- Hermitian split + product (pos p holds freq rev11(p))
#pragma unroll
    for (int i = 0; i < 8; ++i) {
      const int p = t + 256 * i;
      const int f = rev11(p);
      const int fm = (L_ - f) & (L_ - 1);
      const int pm = rev11(fm);
      const float Ar = re1[PADI(p)],  Ai = im1[PADI(p)];
      const float Br = re1[PADI(pm)], Bi = -im1[PADI(pm)];
      const float Qr = 0.5f * (Ar + Br), Qi = 0.5f * (Ai + Bi);
      const float Cr = 0.5f * (Ai - Bi), Ci = 0.5f * (Ar - Br);
      pr[i]  += Qr * Cr - Qi * Ci;
      pi_[i] += Qr * Ci + Qi * Cr;
    }
    // no bottom barrier: next iter's first write targets buf0, whose
    // last readers (exchange 3) finished before the barrier above.
  }

  // plain coalesced stores to the block-private slice (no atomics)
  float2* out = Sp + (size_t)blk * L_;
#pragma unroll
  for (int i = 0; i < 8; ++i) {
    const int p = t + 256 * i;
    out[p] = float2{pr[i], pi_[i]};
  }
}

// ------------------------------------------------------------------
// reduce: S[b][p] = sum over 128 chunks of Sp[b*128+c][p]
// ------------------------------------------------------------------
__global__ __launch_bounds__(256) void reduce_kernel(
    const float2* __restrict__ Sp, float2* __restrict__ S)
{
  const int g = (int)blockIdx.x * 256 + (int)threadIdx.x;   // 0..16383
  const int b = g >> 11;
  const int p = g & (L_ - 1);
  const float2* base = Sp + ((size_t)(b << 7) << 11) + p;
  float sr = 0.f, si = 0.f;
#pragma unroll 8
  for (int c = 0; c < 128; ++c) {
    const float2 v = base[(size_t)c << 11];
    sr += v.x; si += v.y;
  }
  S[g] = float2{sr, si};
}

// ------------------------------------------------------------------
// Inverse DIT (bit-rev in, natural out), per b, 1024 threads.
// S is the full spectrum in bit-rev slot order -> direct load.
// ------------------------------------------------------------------
__global__ __launch_bounds__(1024) void ifft_kernel(
    const float2* __restrict__ S, float* __restrict__ mv)
{
  __shared__ float re[L_];
  __shared__ float im[L_];
  const int b = blockIdx.x;
  for (int p = (int)threadIdx.x; p < L_; p += 1024) {
    const float2 v = S[(size_t)b * L_ + p];
    re[p] = v.x; im[p] = v.y;
  }
  __syncthreads();
  for (int s = 1; s <= LOG2L; ++s) {
    const int half = 1 << (s - 1);
    {
      const int j = (int)threadIdx.x;
      const int pos = j & (half - 1);
      const int i0 = ((j >> (s - 1)) << s) + pos;
      const int i1 = i0 + half;
      const float ang = 3.14159265358979323846f * (float)pos / (float)half;
      float wi, wr;
      __sincosf(ang, &wi, &wr);
      const float br = re[i1], bi = im[i1];
      const float tr = br * wr - bi * wi;
      const float ti = br * wi + bi * wr;
      const float ar = re[i0], ai = im[i0];
      re[i0] = ar + tr; im[i0] = ai + ti;
      re[i1] = ar - tr; im[i1] = ai - ti;
    }
    __syncthreads();
  }
  const float scale = 1.0f / ((float)D_ * (float)L_);
  for (int l = (int)threadIdx.x; l < L_; l += 1024)
    mv[(size_t)b * L_ + l] = re[l] * scale;
}

// ------------------------------------------------------------------
// topk: 1024 threads, shuffle-reduce argmax x7, then softmax.
// ------------------------------------------------------------------
__global__ __launch_bounds__(1024) void topk_kernel(
    const float* __restrict__ mv, int* __restrict__ idx, float* __restrict__ wts)
{
  __shared__ float vals[L_];
  __shared__ float wm[16];
  __shared__ int wi[16];
  __shared__ int chosen[TOPK];
  const int t = (int)threadIdx.x;
  const int lane = t & 63, wv = t >> 6;
  float s0 = 0.f, s1 = 0.f;
#pragma unroll
  for (int b = 0; b < B_; ++b) {
    s0 += mv[(size_t)b * L_ + t];
    s1 += mv[(size_t)b * L_ + t + 1024];
  }
  vals[t] = s0; vals[t + 1024] = s1;
  __syncthreads();
  for (int kk = 0; kk < TOPK; ++kk) {
    float v0 = vals[t]; int i0 = t;
    const float v1 = vals[t + 1024];
    if (v1 > v0) { v0 = v1; i0 = t + 1024; }
#pragma unroll
    for (int off = 32; off; off >>= 1) {
      const float ov = __shfl_xor(v0, off, 64);
      const int oi = __shfl_xor(i0, off, 64);
      if (ov > v0 || (ov == v0 && oi < i0)) { v0 = ov; i0 = oi; }
    }
    if (lane == 0) { wm[wv] = v0; wi[wv] = i0; }
    __syncthreads();
    if (t == 0) {
      float m = wm[0]; int mi = wi[0];
      for (int i2 = 1; i2 < 16; ++i2)
        if (wm[i2] > m || (wm[i2] == m && wi[i2] < mi)) { m = wm[i2]; mi = wi[i2]; }
      chosen[kk] = mi; idx[kk] = mi; vals[mi] = -1e30f;
    }
    __syncthreads();
  }
  if (t < B_) {
    float w[TOPK];
    float mx = -1e30f;
#pragma unroll
    for (int kk = 0; kk < TOPK; ++kk) {
      w[kk] = mv[(size_t)t * L_ + chosen[kk]];
      mx = fmaxf(mx, w[kk]);
    }
    float sum = 0.f;
#pragma unroll
    for (int kk = 0; kk < TOPK; ++kk) { w[kk] = __expf(w[kk] - mx); sum += w[kk]; }
    const float inv = 1.0f / sum;
#pragma unroll
    for (int kk = 0; kk < TOPK; ++kk) wts[t * TOPK + kk] = w[kk] * inv;
  }
}

// ------------------------------------------------------------------
// context: 4 waves/block, one output row per wave, half8 lanes,
// XCD-swizzled (contiguous l-range per XCD).
// ------------------------------------------------------------------
__global__ __launch_bounds__(256) void context_kernel(
    const _Float16* __restrict__ v, const int* __restrict__ idx,
    const float* __restrict__ wts, _Float16* __restrict__ ctx)
{
  const int raw = (int)blockIdx.x;            // 4096
  const int wg = (raw & 7) * 512 + (raw >> 3);
  const int b = wg >> 9;                      // 512 blocks per batch
  const int l = ((wg & 511) << 2) + ((int)threadIdx.x >> 6);
  const int lane = (int)threadIdx.x & 63;
  float acc[8] = {};
#pragma unroll
  for (int kk = 0; kk < TOPK; ++kk) {
    const float w = wts[b * TOPK + kk];
    const int src = (l + idx[kk]) & (L_ - 1);
    const half8 x = *reinterpret_cast<const half8*>(v + ((size_t)(b << LOG2L) + src) * D_ + lane * 8);
#pragma unroll
    for (int j = 0; j < 8; ++j) acc[j] = fmaf(w, (float)x[j], acc[j]);
  }
  half8 o;
#pragma unroll
  for (int j = 0; j < 8; ++j) o[j] = (_Float16)acc[j];
  *reinterpret_cast<half8*>(ctx + ((size_t)(b << LOG2L) + l) * D_ + lane * 8) = o;
}

// ------------------------------------------------------------------
extern "C" void kernel_launch(void* const* d_in, const int* in_sizes, int n_in,
                              void* d_out, int out_size, void* d_ws, size_t ws_size,
                              hipStream_t stream)
{
  (void)in_sizes; (void)n_in; (void)out_size; (void)ws_size;
  const float* Q   = (const float*)d_in[0];
  const float* K   = (const float*)d_in[1];
  const float* V   = (const float*)d_in[2];
  const float* WQ  = (const float*)d_in[3];
  const float* WK  = (const float*)d_in[4];
  const float* WV  = (const float*)d_in[5];
  const float* Wfc = (const float*)d_in[6];
  float* out = (float*)d_out;

  char* ws = (char*)d_ws;
  const size_t sz_h   = (size_t)M_ * D_ * sizeof(_Float16);    // 16.78 MB
  const size_t sz_w16 = (size_t)D_ * D_ * sizeof(_Float16);    // 512 KB
  _Float16*  qT16  = (_Float16*)(ws);
  _Float16*  kT16  = (_Float16*)(ws + sz_h);
  _Float16*  vs16  = (_Float16*)(ws + 2 * sz_h);
  _Float16*  ctx16 = (_Float16*)(ws + 3 * sz_h);
  // Sp (16.78 MB) overlays the vs16 region: live only between
  // corr_fft and reduce; vs16 is written later by the V GEMM.
  float2*    Sp    = (float2*)(ws + 2 * sz_h);
  _Float16*  WQt   = (_Float16*)(ws + 4 * sz_h);
  _Float16*  WKt   = (_Float16*)(ws + 4 * sz_h + sz_w16);
  _Float16*  WVt   = (_Float16*)(ws + 4 * sz_h + 2 * sz_w16);
  _Float16*  Wfct  = (_Float16*)(ws + 4 * sz_h + 3 * sz_w16);
  float2*    S     = (float2*)(ws + 4 * sz_h + 4 * sz_w16);    // 128 KB
  float*     mv    = (float*)((char*)S + (size_t)B_ * L_ * sizeof(float2));
  int*       idx   = (int*)((char*)mv + (size_t)B_ * L_ * sizeof(float));
  float*     wts   = (float*)((char*)idx + 64);

  convw_kernel<<<256, 256, 0, stream>>>(WQ, WK, WV, Wfc, WQt, WKt, WVt, Wfct);

  gemm_f16_kernel<0, 3><<<NWG, 256, 0, stream>>>(Q, nullptr, WQt, nullptr, qT16);
  gemm_f16_kernel<0, 3><<<NWG, 256, 0, stream>>>(K, nullptr, WKt, nullptr, kT16);

  corr_fft_kernel<<<B_ * (D_ / DCHUNK), 256, 0, stream>>>(qT16, kT16, Sp);
  reduce_kernel<<<64, 256, 0, stream>>>(Sp, S);
  ifft_kernel<<<B_, 1024, 0, stream>>>(S, mv);
  topk_kernel<<<1, 1024, 0, stream>>>(mv, idx, wts);

  gemm_f16_kernel<0, 2><<<NWG, 256, 0, stream>>>(V, nullptr, WVt, nullptr, vs16);
  context_kernel<<<4096, 256, 0, stream>>>(vs16, idx, wts, ctx16);
  gemm_f16_kernel<1, 0><<<NWG, 256, 0, stream>>>(nullptr, ctx16, Wfct, out, nullptr);
}

// Round 13
// 166.161 us; speedup vs baseline: 1.1886x; 1.0010x over previous
//
#include <hip/hip_runtime.h>
#include <math.h>

#define B_ 8
#define L_ 2048
#define D_ 512
#define LOG2L 11
#define TOPK 7
#define M_ (B_ * L_)     // 16384

typedef __attribute__((ext_vector_type(8))) _Float16 half8;
typedef __attribute__((ext_vector_type(4))) _Float16 half4;
typedef __attribute__((ext_vector_type(4))) float f32x4;

// ------------------------------------------------------------------
// convw: 4 weight mats fp32 [512][512] (k-major) -> f16 [n][k].
// ------------------------------------------------------------------
__global__ __launch_bounds__(256) void convw_kernel(
    const float* __restrict__ W0, const float* __restrict__ W1,
    const float* __restrict__ W2, const float* __restrict__ W3,
    _Float16* __restrict__ T0, _Float16* __restrict__ T1,
    _Float16* __restrict__ T2, _Float16* __restrict__ T3)
{
  __shared__ float tile[64][65];
  const int t = (int)threadIdx.x;
  const int mat = (int)blockIdx.x >> 6;
  const int tb = (int)blockIdx.x & 63;
  const float* W = (mat == 0) ? W0 : (mat == 1) ? W1 : (mat == 2) ? W2 : W3;
  _Float16* Wt = (mat == 0) ? T0 : (mat == 1) ? T1 : (mat == 2) ? T2 : T3;
  const int k0 = (tb >> 3) * 64;
  const int n0 = (tb & 7) * 64;
#pragma unroll
  for (int i = 0; i < 4; ++i) {
    const int kl = (t >> 4) + i * 16;
    const float4 v = *reinterpret_cast<const float4*>(&W[(size_t)(k0 + kl) * D_ + n0 + (t & 15) * 4]);
    tile[kl][(t & 15) * 4 + 0] = v.x;
    tile[kl][(t & 15) * 4 + 1] = v.y;
    tile[kl][(t & 15) * 4 + 2] = v.z;
    tile[kl][(t & 15) * 4 + 3] = v.w;
  }
  __syncthreads();
  const int nl = t >> 2, q = t & 3;
  half8 h0, h1;
#pragma unroll
  for (int j = 0; j < 8; ++j) {
    h0[j] = (_Float16)tile[q * 16 + j][nl];
    h1[j] = (_Float16)tile[q * 16 + 8 + j][nl];
  }
  _Float16* dst = &Wt[(size_t)(n0 + nl) * D_ + k0 + q * 16];
  *reinterpret_cast<half8*>(dst) = h0;
  *reinterpret_cast<half8*>(dst + 8) = h1;
}

// ------------------------------------------------------------------
// MFMA f16 GEMM: C = A[M,512] @ W using Wt[n][k] f16.
// 64x128 tile, BK=64, 4 waves (2x2: wave tile 32x64), grid 1024
// (4/CU), XCD-swizzled. OUTMODE: 0 = fp32 [M,512]; 2 = f16 [M,512];
// 3 = f16 transposed [512][M] (acc reg idx is m -> half4 store).
// ------------------------------------------------------------------
#define LDSTR 72
#define NWG 1024

template <int INBF, int OUTMODE>
__global__ __launch_bounds__(256) void gemm_f16_kernel(
    const float* __restrict__ Af, const _Float16* __restrict__ Ah,
    const _Float16* __restrict__ Wt,
    float* __restrict__ Cf, _Float16* __restrict__ Ch)
{
  __shared__ __align__(16) _Float16 sA[64 * LDSTR];
  __shared__ __align__(16) _Float16 sB[128 * LDSTR];

  const int bid = (int)blockIdx.x;
  const int wg = (bid & 7) * (NWG >> 3) + (bid >> 3);
  const int m0 = (wg >> 2) << 6;        // 256 m-panels of 64
  const int n0 = (wg & 3) << 7;         // 4 n-panels of 128

  const int tid = (int)threadIdx.x;
  const int lane = tid & 63, wave = tid >> 6;
  const int wr = (wave >> 1) << 5;      // 0 / 32
  const int wc = (wave & 1) << 6;       // 0 / 64

  const int arow = tid >> 2;            // 0..63  (A stage row)
  const int ac0 = (tid & 3) << 4;       // 0,16,32,48
  const int brow = tid >> 1;            // 0..127 (B stage row)
  const int bc0 = (tid & 1) << 5;       // 0 / 32

  f32x4 acc[2][4];
  const f32x4 zero = {0.f, 0.f, 0.f, 0.f};
#pragma unroll
  for (int i = 0; i < 2; ++i)
#pragma unroll
    for (int j = 0; j < 4; ++j) acc[i][j] = zero;

  const int fr = lane & 15;
  const int g8 = (lane >> 4) << 3;

  for (int k0 = 0; k0 < D_; k0 += 64) {
    half8 ha0, ha1, hb0, hb1, hb2, hb3;
    if constexpr (INBF == 0) {
      const float* ap = Af + (size_t)(m0 + arow) * D_ + k0 + ac0;
      float tmp[16];
#pragma unroll
      for (int j = 0; j < 4; ++j) {
        const float4 v = *reinterpret_cast<const float4*>(ap + j * 4);
        tmp[j * 4 + 0] = v.x; tmp[j * 4 + 1] = v.y;
        tmp[j * 4 + 2] = v.z; tmp[j * 4 + 3] = v.w;
      }
#pragma unroll
      for (int j = 0; j < 8; ++j) { ha0[j] = (_Float16)tmp[j]; ha1[j] = (_Float16)tmp[8 + j]; }
    } else {
      const _Float16* ap = Ah + (size_t)(m0 + arow) * D_ + k0 + ac0;
      ha0 = *reinterpret_cast<const half8*>(ap);
      ha1 = *reinterpret_cast<const half8*>(ap + 8);
    }
    {
      const _Float16* bp = Wt + (size_t)(n0 + brow) * D_ + k0 + bc0;
      hb0 = *reinterpret_cast<const half8*>(bp);
      hb1 = *reinterpret_cast<const half8*>(bp + 8);
      hb2 = *reinterpret_cast<const half8*>(bp + 16);
      hb3 = *reinterpret_cast<const half8*>(bp + 24);
    }

    __syncthreads();    // previous iteration's fragment reads done
    *reinterpret_cast<half8*>(&sA[arow * LDSTR + ac0]) = ha0;
    *reinterpret_cast<half8*>(&sA[arow * LDSTR + ac0 + 8]) = ha1;
    *reinterpret_cast<half8*>(&sB[brow * LDSTR + bc0]) = hb0;
    *reinterpret_cast<half8*>(&sB[brow * LDSTR + bc0 + 8]) = hb1;
    *reinterpret_cast<half8*>(&sB[brow * LDSTR + bc0 + 16]) = hb2;
    *reinterpret_cast<half8*>(&sB[brow * LDSTR + bc0 + 24]) = hb3;
    __syncthreads();

#pragma unroll
    for (int ks = 0; ks < 64; ks += 32) {
      half8 afr[2], bfr[4];
#pragma unroll
      for (int i = 0; i < 2; ++i)
        afr[i] = *reinterpret_cast<const half8*>(&sA[(wr + i * 16 + fr) * LDSTR + ks + g8]);
#pragma unroll
      for (int i = 0; i < 4; ++i)
        bfr[i] = *reinterpret_cast<const half8*>(&sB[(wc + i * 16 + fr) * LDSTR + ks + g8]);
#pragma unroll
      for (int mi = 0; mi < 2; ++mi)
#pragma unroll
        for (int ni = 0; ni < 4; ++ni)
          acc[mi][ni] = __builtin_amdgcn_mfma_f32_16x16x32_f16(afr[mi], bfr[ni], acc[mi][ni], 0, 0, 0);
    }
  }

  const int orow = (lane >> 4) << 2;   // m sub-offset (reg idx r adds 0..3)
  const int ocol = lane & 15;          // n sub-offset
  if constexpr (OUTMODE == 0) {
#pragma unroll
    for (int mi = 0; mi < 2; ++mi)
#pragma unroll
      for (int ni = 0; ni < 4; ++ni)
#pragma unroll
        for (int r = 0; r < 4; ++r)
          Cf[(size_t)(m0 + wr + mi * 16 + orow + r) * D_ + n0 + wc + ni * 16 + ocol] = acc[mi][ni][r];
  } else if constexpr (OUTMODE == 2) {
#pragma unroll
    for (int mi = 0; mi < 2; ++mi)
#pragma unroll
      for (int ni = 0; ni < 4; ++ni)
#pragma unroll
        for (int r = 0; r < 4; ++r)
          Ch[(size_t)(m0 + wr + mi * 16 + orow + r) * D_ + n0 + wc + ni * 16 + ocol] = (_Float16)acc[mi][ni][r];
  } else {
    // CT[n][m] f16: acc[mi][ni] holds 4 consecutive m -> half4 store
#pragma unroll
    for (int ni = 0; ni < 4; ++ni) {
      const size_t nrow = (size_t)(n0 + wc + ni * 16 + ocol) * M_;
#pragma unroll
      for (int mi = 0; mi < 2; ++mi) {
        half4 hv;
        hv[0] = (_Float16)acc[mi][ni][0]; hv[1] = (_Float16)acc[mi][ni][1];
        hv[2] = (_Float16)acc[mi][ni][2]; hv[3] = (_Float16)acc[mi][ni][3];
        *reinterpret_cast<half4*>(&Ch[nrow + m0 + wr + mi * 16 + orow]) = hv;
      }
    }
  }
}

// ------------------------------------------------------------------
// corr_fft v8: double-buffered register FFT, DCHUNK=2 (2048 blocks =
// 8/CU for latency hiding), private-slice stores (no atomics).
// ------------------------------------------------------------------
__device__ __forceinline__ int rev11(int x) {
  return (int)(__brev((unsigned)x) >> (32 - LOG2L));
}

#define DCHUNK 2
#define PADI(i) ((i) + ((i) >> 5))

#define BFLY(j0, j1, wr_, wi_) { \
  const float ar = xr[j0], ai = xi[j0], br = xr[j1], bi = xi[j1]; \
  xr[j0] = ar + br; xi[j0] = ai + bi; \
  const float tr = ar - br, ti = ai - bi; \
  xr[j1] = tr * (wr_) - ti * (wi_); \
  xi[j1] = tr * (wi_) + ti * (wr_); }

__global__ __launch_bounds__(256) void corr_fft_kernel(
    const _Float16* __restrict__ qT, const _Float16* __restrict__ kT,
    float2* __restrict__ Sp)
{
  __shared__ float re0[2112], im0[2112];
  __shared__ float re1[2112], im1[2112];
  const int t = (int)threadIdx.x;
  const int blk = (int)blockIdx.x;
  const int b = blk >> 8;                   // 256 chunks per batch
  const int d0 = (blk & 255) * DCHUNK;
  const int u2 = t & 31, u3 = t & 3;

  float w2048r, w2048i, w256r, w256i, w32r, w32i;
  {
    float s_, c_;
    __sincosf(-6.283185307179586f * (float)t / 2048.f, &s_, &c_);
    w2048r = c_; w2048i = s_;
    __sincosf(-6.283185307179586f * (float)u2 / 256.f, &s_, &c_);
    w256r = c_; w256i = s_;
    __sincosf(-6.283185307179586f * (float)u3 / 32.f, &s_, &c_);
    w32r = c_; w32i = s_;
  }
  const float w1024r = w2048r * w2048r - w2048i * w2048i, w1024i = 2.f * w2048r * w2048i;
  const float w512r  = w1024r * w1024r - w1024i * w1024i, w512i  = 2.f * w1024r * w1024i;
  const float w128r  = w256r * w256r - w256i * w256i,     w128i  = 2.f * w256r * w256i;
  const float w64r   = w128r * w128r - w128i * w128i,     w64i   = 2.f * w128r * w128i;
  const float w16r   = w32r * w32r - w32i * w32i,         w16i   = 2.f * w32r * w32i;
  const float w8r    = w16r * w16r - w16i * w16i,         w8i    = 2.f * w16r * w16i;

  const float C_ = 0.70710678118654752f;
  const float W8R[4] = {1.f, C_, 0.f, -C_};
  const float W8I[4] = {0.f, -C_, -1.f, -C_};

  float pr[8] = {}, pi_[8] = {};

  for (int dc = 0; dc < DCHUNK; ++dc) {
    const int d = d0 + dc;
    const _Float16* qrow = qT + (size_t)d * M_ + (size_t)b * L_;
    const _Float16* krow = kT + (size_t)d * M_ + (size_t)b * L_;

    float xr[8], xi[8];
#pragma unroll
    for (int j = 0; j < 8; ++j) {
      xr[j] = (float)qrow[t + 256 * j];
      xi[j] = (float)krow[t + 256 * j];
    }

    // ---- round 1: stages half=1024,512,256
#pragma unroll
    for (int j = 0; j < 4; ++j) {
      const float wr_ = w2048r * W8R[j] - w2048i * W8I[j];
      const float wi_ = w2048r * W8I[j] + w2048i * W8R[j];
      BFLY(j, j + 4, wr_, wi_);
    }
#pragma unroll
    for (int base = 0; base < 8; base += 4) {
      BFLY(base + 0, base + 2, w1024r, w1024i);
      BFLY(base + 1, base + 3, w1024i, -w1024r);
    }
#pragma unroll
    for (int a = 0; a < 8; a += 2) BFLY(a, a + 1, w512r, w512i);

    // ---- exchange 1 (buf0): pos t+256j -> (t>>5)*256 + (t&31) + 32j
#pragma unroll
    for (int j = 0; j < 8; ++j) {
      const int p = t + 256 * j;
      re0[PADI(p)] = xr[j]; im0[PADI(p)] = xi[j];
    }
    __syncthreads();
#pragma unroll
    for (int j = 0; j < 8; ++j) {
      const int p = ((t >> 5) << 8) + u2 + 32 * j;
      xr[j] = re0[PADI(p)]; xi[j] = im0[PADI(p)];
    }

    // ---- round 2: stages half=128,64,32
#pragma unroll
    for (int j = 0; j < 4; ++j) {
      const float wr_ = w256r * W8R[j] - w256i * W8I[j];
      const float wi_ = w256r * W8I[j] + w256i * W8R[j];
      BFLY(j, j + 4, wr_, wi_);
    }
#pragma unroll
    for (int base = 0; base < 8; base += 4) {
      BFLY(base + 0, base + 2, w128r, w128i);
      BFLY(base + 1, base + 3, w128i, -w128r);
    }
#pragma unroll
    for (int a = 0; a < 8; a += 2) BFLY(a, a + 1, w64r, w64i);

    // ---- exchange 2 (buf1) -> (t>>2)*32 + (t&3) + 4j
#pragma unroll
    for (int j = 0; j < 8; ++j) {
      const int p = ((t >> 5) << 8) + u2 + 32 * j;
      re1[PADI(p)] = xr[j]; im1[PADI(p)] = xi[j];
    }
    __syncthreads();
#pragma unroll
    for (int j = 0; j < 8; ++j) {
      const int p = ((t >> 2) << 5) + u3 + 4 * j;
      xr[j] = re1[PADI(p)]; xi[j] = im1[PADI(p)];
    }

    // ---- round 3: stages half=16,8,4
#pragma unroll
    for (int j = 0; j < 4; ++j) {
      const float wr_ = w32r * W8R[j] - w32i * W8I[j];
      const float wi_ = w32r * W8I[j] + w32i * W8R[j];
      BFLY(j, j + 4, wr_, wi_);
    }
#pragma unroll
    for (int base = 0; base < 8; base += 4) {
      BFLY(base + 0, base + 2, w16r, w16i);
      BFLY(base + 1, base + 3, w16i, -w16r);
    }
#pragma unroll
    for (int a = 0; a < 8; a += 2) BFLY(a, a + 1, w8r, w8i);

    // ---- exchange 3 (buf0) -> pos 8t+j
#pragma unroll
    for (int j = 0; j < 8; ++j) {
      const int p = ((t >> 2) << 5) + u3 + 4 * j;
      re0[PADI(p)] = xr[j]; im0[PADI(p)] = xi[j];
    }
    __syncthreads();
#pragma unroll
    for (int j = 0; j < 8; ++j) {
      const int p = 8 * t + j;
      xr[j] = re0[PADI(p)]; xi[j] = im0[PADI(p)];
    }

    // ---- round 4: stages half=2,1
#pragma unroll
    for (int base = 0; base < 8; base += 4) {
      BFLY(base + 0, base + 2, 1.f, 0.f);
      BFLY(base + 1, base + 3, 0.f, -1.f);
    }
#pragma unroll
    for (int a = 0; a < 8; a += 2) BFLY(a, a + 1, 1.f, 0.f);

    // ---- final write (buf1), then Hermitian split
#pragma unroll
    for (int j = 0; j < 8; ++j) {
      const int p = 8 * t + j;
      re1[PADI(p)] = xr[j]; im1[PADI(p)] = xi[j];
    }
    __syncthreads();

    // ---- Hermitian split + product (pos p holds freq rev11(p))
#pragma unroll
    for (int i = 0; i < 8; ++i) {
      const int p = t + 256 * i;
      const int f = rev11(p);
      const int fm = (L_ - f) & (L_ - 1);
      const int pm = rev11(fm);
      const float Ar = re1[PADI(p)],  Ai = im1[PADI(p)];
      const float Br = re1[PADI(pm)], Bi = -im1[PADI(pm)];
      const float Qr = 0.5f * (Ar + Br), Qi = 0.5f * (Ai + Bi);
      const float Cr = 0.5f * (Ai - Bi), Ci = 0.5f * (Ar - Br);
      pr[i]  += Qr * Cr - Qi * Ci;
      pi_[i] += Qr * Ci + Qi * Cr;
    }
    if (dc + 1 < DCHUNK) __syncthreads();  // buf1 re-written next iter's exch2
  }

  // plain coalesced stores to the block-private slice (no atomics)
  float2* out = Sp + (size_t)blk * L_;
#pragma unroll
  for (int i = 0; i < 8; ++i) {
    const int p = t + 256 * i;
    out[p] = float2{pr[i], pi_[i]};
  }
}

// ------------------------------------------------------------------
// reduce v2: S[b][p] = sum over 256 chunks of Sp[b*256+c][p].
// 512 blocks: block = (b, pgroup of 32 p); 256 thr = 32 p x 8 c-subs
// (32 chunks each); LDS tree over the 8 partials.
// ------------------------------------------------------------------
__global__ __launch_bounds__(256) void reduce_kernel(
    const float2* __restrict__ Sp, float2* __restrict__ S)
{
  __shared__ float psr[8][33];
  __shared__ float psi[8][33];
  const int bid = (int)blockIdx.x;          // 512
  const int b = bid >> 6;
  const int pg = bid & 63;
  const int t = (int)threadIdx.x;
  const int pl = t & 31;                    // p within group
  const int cs = t >> 5;                    // 0..7
  const int p = (pg << 5) + pl;
  const float2* base = Sp + (((size_t)b << 8) << 11) + p;
  float sr = 0.f, si = 0.f;
#pragma unroll 8
  for (int c = cs * 32; c < cs * 32 + 32; ++c) {
    const float2 v = base[(size_t)c << 11];
    sr += v.x; si += v.y;
  }
  psr[cs][pl] = sr; psi[cs][pl] = si;
  __syncthreads();
  if (t < 32) {
    float tr = 0.f, ti = 0.f;
#pragma unroll
    for (int s = 0; s < 8; ++s) { tr += psr[s][t]; ti += psi[s][t]; }
    S[((size_t)b << 11) + (pg << 5) + t] = float2{tr, ti};
  }
}

// ------------------------------------------------------------------
// Inverse DIT (bit-rev in, natural out), per b, 1024 threads.
// S is the full spectrum in bit-rev slot order -> direct load.
// ------------------------------------------------------------------
__global__ __launch_bounds__(1024) void ifft_kernel(
    const float2* __restrict__ S, float* __restrict__ mv)
{
  __shared__ float re[L_];
  __shared__ float im[L_];
  const int b = blockIdx.x;
  for (int p = (int)threadIdx.x; p < L_; p += 1024) {
    const float2 v = S[(size_t)b * L_ + p];
    re[p] = v.x; im[p] = v.y;
  }
  __syncthreads();
  for (int s = 1; s <= LOG2L; ++s) {
    const int half = 1 << (s - 1);
    {
      const int j = (int)threadIdx.x;
      const int pos = j & (half - 1);
      const int i0 = ((j >> (s - 1)) << s) + pos;
      const int i1 = i0 + half;
      const float ang = 3.14159265358979323846f * (float)pos / (float)half;
      float wi, wr;
      __sincosf(ang, &wi, &wr);
      const float br = re[i1], bi = im[i1];
      const float tr = br * wr - bi * wi;
      const float ti = br * wi + bi * wr;
      const float ar = re[i0], ai = im[i0];
      re[i0] = ar + tr; im[i0] = ai + ti;
      re[i1] = ar - tr; im[i1] = ai - ti;
    }
    __syncthreads();
  }
  const float scale = 1.0f / ((float)D_ * (float)L_);
  for (int l = (int)threadIdx.x; l < L_; l += 1024)
    mv[(size_t)b * L_ + l] = re[l] * scale;
}

// ------------------------------------------------------------------
// topk: 1024 threads, shuffle-reduce argmax x7, then softmax.
// ------------------------------------------------------------------
__global__ __launch_bounds__(1024) void topk_kernel(
    const float* __restrict__ mv, int* __restrict__ idx, float* __restrict__ wts)
{
  __shared__ float vals[L_];
  __shared__ float wm[16];
  __shared__ int wi[16];
  __shared__ int chosen[TOPK];
  const int t = (int)threadIdx.x;
  const int lane = t & 63, wv = t >> 6;
  float s0 = 0.f, s1 = 0.f;
#pragma unroll
  for (int b = 0; b < B_; ++b) {
    s0 += mv[(size_t)b * L_ + t];
    s1 += mv[(size_t)b * L_ + t + 1024];
  }
  vals[t] = s0; vals[t + 1024] = s1;
  __syncthreads();
  for (int kk = 0; kk < TOPK; ++kk) {
    float v0 = vals[t]; int i0 = t;
    const float v1 = vals[t + 1024];
    if (v1 > v0) { v0 = v1; i0 = t + 1024; }
#pragma unroll
    for (int off = 32; off; off >>= 1) {
      const float ov = __shfl_xor(v0, off, 64);
      const int oi = __shfl_xor(i0, off, 64);
      if (ov > v0 || (ov == v0 && oi < i0)) { v0 = ov; i0 = oi; }
    }
    if (lane == 0) { wm[wv] = v0; wi[wv] = i0; }
    __syncthreads();
    if (t == 0) {
      float m = wm[0]; int mi = wi[0];
      for (int i2 = 1; i2 < 16; ++i2)
        if (wm[i2] > m || (wm[i2] == m && wi[i2] < mi)) { m = wm[i2]; mi = wi[i2]; }
      chosen[kk] = mi; idx[kk] = mi; vals[mi] = -1e30f;
    }
    __syncthreads();
  }
  if (t < B_) {
    float w[TOPK];
    float mx = -1e30f;
#pragma unroll
    for (int kk = 0; kk < TOPK; ++kk) {
      w[kk] = mv[(size_t)t * L_ + chosen[kk]];
      mx = fmaxf(mx, w[kk]);
    }
    float sum = 0.f;
#pragma unroll
    for (int kk = 0; kk < TOPK; ++kk) { w[kk] = __expf(w[kk] - mx); sum += w[kk]; }
    const float inv = 1.0f / sum;
#pragma unroll
    for (int kk = 0; kk < TOPK; ++kk) wts[t * TOPK + kk] = w[kk] * inv;
  }
}

// ------------------------------------------------------------------
// context: 4 waves/block, one output row per wave, half8 lanes,
// XCD-swizzled (contiguous l-range per XCD).
// ------------------------------------------------------------------
__global__ __launch_bounds__(256) void context_kernel(
    const _Float16* __restrict__ v, const int* __restrict__ idx,
    const float* __restrict__ wts, _Float16* __restrict__ ctx)
{
  const int raw = (int)blockIdx.x;            // 4096
  const int wg = (raw & 7) * 512 + (raw >> 3);
  const int b = wg >> 9;                      // 512 blocks per batch
  const int l = ((wg & 511) << 2) + ((int)threadIdx.x >> 6);
  const int lane = (int)threadIdx.x & 63;
  float acc[8] = {};
#pragma unroll
  for (int kk = 0; kk < TOPK; ++kk) {
    const float w = wts[b * TOPK + kk];
    const int src = (l + idx[kk]) & (L_ - 1);
    const half8 x = *reinterpret_cast<const half8*>(v + ((size_t)(b << LOG2L) + src) * D_ + lane * 8);
#pragma unroll
    for (int j = 0; j < 8; ++j) acc[j] = fmaf(w, (float)x[j], acc[j]);
  }
  half8 o;
#pragma unroll
  for (int j = 0; j < 8; ++j) o[j] = (_Float16)acc[j];
  *reinterpret_cast<half8*>(ctx + ((size_t)(b << LOG2L) + l) * D_ + lane * 8) = o;
}

// ------------------------------------------------------------------
extern "C" void kernel_launch(void* const* d_in, const int* in_sizes, int n_in,
                              void* d_out, int out_size, void* d_ws, size_t ws_size,
                              hipStream_t stream)
{
  (void)in_sizes; (void)n_in; (void)out_size; (void)ws_size;
  const float* Q   = (const float*)d_in[0];
  const float* K   = (const float*)d_in[1];
  const float* V   = (const float*)d_in[2];
  const float* WQ  = (const float*)d_in[3];
  const float* WK  = (const float*)d_in[4];
  const float* WV  = (const float*)d_in[5];
  const float* Wfc = (const float*)d_in[6];
  float* out = (float*)d_out;

  char* ws = (char*)d_ws;
  const size_t sz_h   = (size_t)M_ * D_ * sizeof(_Float16);    // 16.78 MB
  const size_t sz_w16 = (size_t)D_ * D_ * sizeof(_Float16);    // 512 KB
  _Float16*  qT16  = (_Float16*)(ws);
  _Float16*  kT16  = (_Float16*)(ws + sz_h);
  _Float16*  vs16  = (_Float16*)(ws + 2 * sz_h);
  _Float16*  ctx16 = (_Float16*)(ws + 3 * sz_h);
  _Float16*  WQt   = (_Float16*)(ws + 4 * sz_h);
  _Float16*  WKt   = (_Float16*)(ws + 4 * sz_h + sz_w16);
  _Float16*  WVt   = (_Float16*)(ws + 4 * sz_h + 2 * sz_w16);
  _Float16*  Wfct  = (_Float16*)(ws + 4 * sz_h + 3 * sz_w16);
  float2*    S     = (float2*)(ws + 4 * sz_h + 4 * sz_w16);    // 128 KB
  float*     mv    = (float*)((char*)S + (size_t)B_ * L_ * sizeof(float2));
  int*       idx   = (int*)((char*)mv + (size_t)B_ * L_ * sizeof(float));
  float*     wts   = (float*)((char*)idx + 64);
  // Sp: 2048 slices x 2048 float2 = 33.55 MB, dedicated region
  float2*    Sp    = (float2*)(ws + 5 * sz_h + 8 * sz_w16);

  convw_kernel<<<256, 256, 0, stream>>>(WQ, WK, WV, Wfc, WQt, WKt, WVt, Wfct);

  gemm_f16_kernel<0, 3><<<NWG, 256, 0, stream>>>(Q, nullptr, WQt, nullptr, qT16);
  gemm_f16_kernel<0, 3><<<NWG, 256, 0, stream>>>(K, nullptr, WKt, nullptr, kT16);

  corr_fft_kernel<<<B_ * (D_ / DCHUNK), 256, 0, stream>>>(qT16, kT16, Sp);
  reduce_kernel<<<512, 256, 0, stream>>>(Sp, S);
  ifft_kernel<<<B_, 1024, 0, stream>>>(S, mv);
  topk_kernel<<<1, 1024, 0, stream>>>(mv, idx, wts);

  gemm_f16_kernel<0, 2><<<NWG, 256, 0, stream>>>(V, nullptr, WVt, nullptr, vs16);
  context_kernel<<<4096, 256, 0, stream>>>(vs16, idx, wts, ctx16);
  gemm_f16_kernel<1, 0><<<NWG, 256, 0, stream>>>(nullptr, ctx16, Wfct, out, nullptr);
}

// Round 14
// 158.283 us; speedup vs baseline: 1.2478x; 1.0498x over previous
//
#include <hip/hip_runtime.h>
#include <math.h>

#define B_ 8
#define L_ 2048
#define D_ 512
#define LOG2L 11
#define TOPK 7
#define M_ (B_ * L_)     // 16384

typedef __attribute__((ext_vector_type(8))) _Float16 half8;
typedef __attribute__((ext_vector_type(4))) _Float16 half4;
typedef __attribute__((ext_vector_type(4))) float f32x4;

// ------------------------------------------------------------------
// convw: 4 weight mats fp32 [512][512] (k-major) -> f16 [n][k].
// ------------------------------------------------------------------
__global__ __launch_bounds__(256) void convw_kernel(
    const float* __restrict__ W0, const float* __restrict__ W1,
    const float* __restrict__ W2, const float* __restrict__ W3,
    _Float16* __restrict__ T0, _Float16* __restrict__ T1,
    _Float16* __restrict__ T2, _Float16* __restrict__ T3)
{
  __shared__ float tile[64][65];
  const int t = (int)threadIdx.x;
  const int mat = (int)blockIdx.x >> 6;
  const int tb = (int)blockIdx.x & 63;
  const float* W = (mat == 0) ? W0 : (mat == 1) ? W1 : (mat == 2) ? W2 : W3;
  _Float16* Wt = (mat == 0) ? T0 : (mat == 1) ? T1 : (mat == 2) ? T2 : T3;
  const int k0 = (tb >> 3) * 64;
  const int n0 = (tb & 7) * 64;
#pragma unroll
  for (int i = 0; i < 4; ++i) {
    const int kl = (t >> 4) + i * 16;
    const float4 v = *reinterpret_cast<const float4*>(&W[(size_t)(k0 + kl) * D_ + n0 + (t & 15) * 4]);
    tile[kl][(t & 15) * 4 + 0] = v.x;
    tile[kl][(t & 15) * 4 + 1] = v.y;
    tile[kl][(t & 15) * 4 + 2] = v.z;
    tile[kl][(t & 15) * 4 + 3] = v.w;
  }
  __syncthreads();
  const int nl = t >> 2, q = t & 3;
  half8 h0, h1;
#pragma unroll
  for (int j = 0; j < 8; ++j) {
    h0[j] = (_Float16)tile[q * 16 + j][nl];
    h1[j] = (_Float16)tile[q * 16 + 8 + j][nl];
  }
  _Float16* dst = &Wt[(size_t)(n0 + nl) * D_ + k0 + q * 16];
  *reinterpret_cast<half8*>(dst) = h0;
  *reinterpret_cast<half8*>(dst + 8) = h1;
}

// ------------------------------------------------------------------
// MFMA f16 GEMM: C = A[M,512] @ W using Wt[n][k] f16.
// 64x128 tile, BK=64, 4 waves (2x2: wave tile 32x64), grid 1024
// (4/CU), XCD-swizzled. OUTMODE: 0 = fp32 [M,512]; 2 = f16 [M,512];
// 3 = f16 transposed [512][M] (acc reg idx is m -> half4 store).
// ------------------------------------------------------------------
#define LDSTR 72
#define NWG 1024

template <int INBF, int OUTMODE>
__global__ __launch_bounds__(256) void gemm_f16_kernel(
    const float* __restrict__ Af, const _Float16* __restrict__ Ah,
    const _Float16* __restrict__ Wt,
    float* __restrict__ Cf, _Float16* __restrict__ Ch)
{
  __shared__ __align__(16) _Float16 sA[64 * LDSTR];
  __shared__ __align__(16) _Float16 sB[128 * LDSTR];

  const int bid = (int)blockIdx.x;
  const int wg = (bid & 7) * (NWG >> 3) + (bid >> 3);
  const int m0 = (wg >> 2) << 6;        // 256 m-panels of 64
  const int n0 = (wg & 3) << 7;         // 4 n-panels of 128

  const int tid = (int)threadIdx.x;
  const int lane = tid & 63, wave = tid >> 6;
  const int wr = (wave >> 1) << 5;      // 0 / 32
  const int wc = (wave & 1) << 6;       // 0 / 64

  const int arow = tid >> 2;            // 0..63  (A stage row)
  const int ac0 = (tid & 3) << 4;       // 0,16,32,48
  const int brow = tid >> 1;            // 0..127 (B stage row)
  const int bc0 = (tid & 1) << 5;       // 0 / 32

  f32x4 acc[2][4];
  const f32x4 zero = {0.f, 0.f, 0.f, 0.f};
#pragma unroll
  for (int i = 0; i < 2; ++i)
#pragma unroll
    for (int j = 0; j < 4; ++j) acc[i][j] = zero;

  const int fr = lane & 15;
  const int g8 = (lane >> 4) << 3;

  for (int k0 = 0; k0 < D_; k0 += 64) {
    half8 ha0, ha1, hb0, hb1, hb2, hb3;
    if constexpr (INBF == 0) {
      const float* ap = Af + (size_t)(m0 + arow) * D_ + k0 + ac0;
      float tmp[16];
#pragma unroll
      for (int j = 0; j < 4; ++j) {
        const float4 v = *reinterpret_cast<const float4*>(ap + j * 4);
        tmp[j * 4 + 0] = v.x; tmp[j * 4 + 1] = v.y;
        tmp[j * 4 + 2] = v.z; tmp[j * 4 + 3] = v.w;
      }
#pragma unroll
      for (int j = 0; j < 8; ++j) { ha0[j] = (_Float16)tmp[j]; ha1[j] = (_Float16)tmp[8 + j]; }
    } else {
      const _Float16* ap = Ah + (size_t)(m0 + arow) * D_ + k0 + ac0;
      ha0 = *reinterpret_cast<const half8*>(ap);
      ha1 = *reinterpret_cast<const half8*>(ap + 8);
    }
    {
      const _Float16* bp = Wt + (size_t)(n0 + brow) * D_ + k0 + bc0;
      hb0 = *reinterpret_cast<const half8*>(bp);
      hb1 = *reinterpret_cast<const half8*>(bp + 8);
      hb2 = *reinterpret_cast<const half8*>(bp + 16);
      hb3 = *reinterpret_cast<const half8*>(bp + 24);
    }

    __syncthreads();    // previous iteration's fragment reads done
    *reinterpret_cast<half8*>(&sA[arow * LDSTR + ac0]) = ha0;
    *reinterpret_cast<half8*>(&sA[arow * LDSTR + ac0 + 8]) = ha1;
    *reinterpret_cast<half8*>(&sB[brow * LDSTR + bc0]) = hb0;
    *reinterpret_cast<half8*>(&sB[brow * LDSTR + bc0 + 8]) = hb1;
    *reinterpret_cast<half8*>(&sB[brow * LDSTR + bc0 + 16]) = hb2;
    *reinterpret_cast<half8*>(&sB[brow * LDSTR + bc0 + 24]) = hb3;
    __syncthreads();

#pragma unroll
    for (int ks = 0; ks < 64; ks += 32) {
      half8 afr[2], bfr[4];
#pragma unroll
      for (int i = 0; i < 2; ++i)
        afr[i] = *reinterpret_cast<const half8*>(&sA[(wr + i * 16 + fr) * LDSTR + ks + g8]);
#pragma unroll
      for (int i = 0; i < 4; ++i)
        bfr[i] = *reinterpret_cast<const half8*>(&sB[(wc + i * 16 + fr) * LDSTR + ks + g8]);
#pragma unroll
      for (int mi = 0; mi < 2; ++mi)
#pragma unroll
        for (int ni = 0; ni < 4; ++ni)
          acc[mi][ni] = __builtin_amdgcn_mfma_f32_16x16x32_f16(afr[mi], bfr[ni], acc[mi][ni], 0, 0, 0);
    }
  }

  const int orow = (lane >> 4) << 2;   // m sub-offset (reg idx r adds 0..3)
  const int ocol = lane & 15;          // n sub-offset
  if constexpr (OUTMODE == 0) {
#pragma unroll
    for (int mi = 0; mi < 2; ++mi)
#pragma unroll
      for (int ni = 0; ni < 4; ++ni)
#pragma unroll
        for (int r = 0; r < 4; ++r)
          Cf[(size_t)(m0 + wr + mi * 16 + orow + r) * D_ + n0 + wc + ni * 16 + ocol] = acc[mi][ni][r];
  } else if constexpr (OUTMODE == 2) {
#pragma unroll
    for (int mi = 0; mi < 2; ++mi)
#pragma unroll
      for (int ni = 0; ni < 4; ++ni)
#pragma unroll
        for (int r = 0; r < 4; ++r)
          Ch[(size_t)(m0 + wr + mi * 16 + orow + r) * D_ + n0 + wc + ni * 16 + ocol] = (_Float16)acc[mi][ni][r];
  } else {
    // CT[n][m] f16: acc[mi][ni] holds 4 consecutive m -> half4 store
#pragma unroll
    for (int ni = 0; ni < 4; ++ni) {
      const size_t nrow = (size_t)(n0 + wc + ni * 16 + ocol) * M_;
#pragma unroll
      for (int mi = 0; mi < 2; ++mi) {
        half4 hv;
        hv[0] = (_Float16)acc[mi][ni][0]; hv[1] = (_Float16)acc[mi][ni][1];
        hv[2] = (_Float16)acc[mi][ni][2]; hv[3] = (_Float16)acc[mi][ni][3];
        *reinterpret_cast<half4*>(&Ch[nrow + m0 + wr + mi * 16 + orow]) = hv;
      }
    }
  }
}

// ------------------------------------------------------------------
// corr_fft v9: TWO FFTs per block in flight (d0, d0+1), fully
// interleaved in registers; FFT-A uses bufA, FFT-B uses bufB.
// Doubles per-wave ILP between barriers; twiddles amortized over 2.
// 2048 blocks; private-slice stores (no atomics).
// ------------------------------------------------------------------
__device__ __forceinline__ int rev11(int x) {
  return (int)(__brev((unsigned)x) >> (32 - LOG2L));
}

#define PADI(i) ((i) + ((i) >> 5))

#define BF(xr, xi, j0, j1, wr_, wi_) { \
  const float ar = xr[j0], ai = xi[j0], br = xr[j1], bi = xi[j1]; \
  xr[j0] = ar + br; xi[j0] = ai + bi; \
  const float tr = ar - br, ti = ai - bi; \
  xr[j1] = tr * (wr_) - ti * (wi_); \
  xi[j1] = tr * (wi_) + ti * (wr_); }

__global__ __launch_bounds__(256) void corr_fft_kernel(
    const _Float16* __restrict__ qT, const _Float16* __restrict__ kT,
    float2* __restrict__ Sp)
{
  __shared__ float reA[2112], imA[2112];
  __shared__ float reB[2112], imB[2112];
  const int t = (int)threadIdx.x;
  const int blk = (int)blockIdx.x;
  const int b = blk >> 8;                   // 256 chunks per batch
  const int d0 = (blk & 255) * 2;
  const int u2 = t & 31, u3 = t & 3;

  float w2048r, w2048i, w256r, w256i, w32r, w32i;
  {
    float s_, c_;
    __sincosf(-6.283185307179586f * (float)t / 2048.f, &s_, &c_);
    w2048r = c_; w2048i = s_;
    __sincosf(-6.283185307179586f * (float)u2 / 256.f, &s_, &c_);
    w256r = c_; w256i = s_;
    __sincosf(-6.283185307179586f * (float)u3 / 32.f, &s_, &c_);
    w32r = c_; w32i = s_;
  }
  const float w1024r = w2048r * w2048r - w2048i * w2048i, w1024i = 2.f * w2048r * w2048i;
  const float w512r  = w1024r * w1024r - w1024i * w1024i, w512i  = 2.f * w1024r * w1024i;
  const float w128r  = w256r * w256r - w256i * w256i,     w128i  = 2.f * w256r * w256i;
  const float w64r   = w128r * w128r - w128i * w128i,     w64i   = 2.f * w128r * w128i;
  const float w16r   = w32r * w32r - w32i * w32i,         w16i   = 2.f * w32r * w32i;
  const float w8r    = w16r * w16r - w16i * w16i,         w8i    = 2.f * w16r * w16i;

  const float C_ = 0.70710678118654752f;
  const float W8R[4] = {1.f, C_, 0.f, -C_};
  const float W8I[4] = {0.f, -C_, -1.f, -C_};

  const _Float16* qA = qT + (size_t)d0 * M_ + (size_t)b * L_;
  const _Float16* kA = kT + (size_t)d0 * M_ + (size_t)b * L_;
  const _Float16* qB = qA + M_;
  const _Float16* kB = kA + M_;

  float xrA[8], xiA[8], xrB[8], xiB[8];
#pragma unroll
  for (int j = 0; j < 8; ++j) {
    xrA[j] = (float)qA[t + 256 * j];
    xiA[j] = (float)kA[t + 256 * j];
    xrB[j] = (float)qB[t + 256 * j];
    xiB[j] = (float)kB[t + 256 * j];
  }

  // ---- round 1: stages half=1024,512,256
#pragma unroll
  for (int j = 0; j < 4; ++j) {
    const float wr_ = w2048r * W8R[j] - w2048i * W8I[j];
    const float wi_ = w2048r * W8I[j] + w2048i * W8R[j];
    BF(xrA, xiA, j, j + 4, wr_, wi_);
    BF(xrB, xiB, j, j + 4, wr_, wi_);
  }
#pragma unroll
  for (int base = 0; base < 8; base += 4) {
    BF(xrA, xiA, base + 0, base + 2, w1024r, w1024i);
    BF(xrA, xiA, base + 1, base + 3, w1024i, -w1024r);
    BF(xrB, xiB, base + 0, base + 2, w1024r, w1024i);
    BF(xrB, xiB, base + 1, base + 3, w1024i, -w1024r);
  }
#pragma unroll
  for (int a = 0; a < 8; a += 2) {
    BF(xrA, xiA, a, a + 1, w512r, w512i);
    BF(xrB, xiB, a, a + 1, w512r, w512i);
  }

  // ---- exchange 1: pos t+256j -> (t>>5)*256 + (t&31) + 32j
#pragma unroll
  for (int j = 0; j < 8; ++j) {
    const int p = PADI(t + 256 * j);
    reA[p] = xrA[j]; imA[p] = xiA[j];
    reB[p] = xrB[j]; imB[p] = xiB[j];
  }
  __syncthreads();
#pragma unroll
  for (int j = 0; j < 8; ++j) {
    const int p = PADI(((t >> 5) << 8) + u2 + 32 * j);
    xrA[j] = reA[p]; xiA[j] = imA[p];
    xrB[j] = reB[p]; xiB[j] = imB[p];
  }

  // ---- round 2: stages half=128,64,32
#pragma unroll
  for (int j = 0; j < 4; ++j) {
    const float wr_ = w256r * W8R[j] - w256i * W8I[j];
    const float wi_ = w256r * W8I[j] + w256i * W8R[j];
    BF(xrA, xiA, j, j + 4, wr_, wi_);
    BF(xrB, xiB, j, j + 4, wr_, wi_);
  }
#pragma unroll
  for (int base = 0; base < 8; base += 4) {
    BF(xrA, xiA, base + 0, base + 2, w128r, w128i);
    BF(xrA, xiA, base + 1, base + 3, w128i, -w128r);
    BF(xrB, xiB, base + 0, base + 2, w128r, w128i);
    BF(xrB, xiB, base + 1, base + 3, w128i, -w128r);
  }
#pragma unroll
  for (int a = 0; a < 8; a += 2) {
    BF(xrA, xiA, a, a + 1, w64r, w64i);
    BF(xrB, xiB, a, a + 1, w64r, w64i);
  }

  // ---- exchange 2 -> (t>>2)*32 + (t&3) + 4j
  __syncthreads();   // protect exch1 reads before overwrite
#pragma unroll
  for (int j = 0; j < 8; ++j) {
    const int p = PADI(((t >> 5) << 8) + u2 + 32 * j);
    reA[p] = xrA[j]; imA[p] = xiA[j];
    reB[p] = xrB[j]; imB[p] = xiB[j];
  }
  __syncthreads();
#pragma unroll
  for (int j = 0; j < 8; ++j) {
    const int p = PADI(((t >> 2) << 5) + u3 + 4 * j);
    xrA[j] = reA[p]; xiA[j] = imA[p];
    xrB[j] = reB[p]; xiB[j] = imB[p];
  }

  // ---- round 3: stages half=16,8,4
#pragma unroll
  for (int j = 0; j < 4; ++j) {
    const float wr_ = w32r * W8R[j] - w32i * W8I[j];
    const float wi_ = w32r * W8I[j] + w32i * W8R[j];
    BF(xrA, xiA, j, j + 4, wr_, wi_);
    BF(xrB, xiB, j, j + 4, wr_, wi_);
  }
#pragma unroll
  for (int base = 0; base < 8; base += 4) {
    BF(xrA, xiA, base + 0, base + 2, w16r, w16i);
    BF(xrA, xiA, base + 1, base + 3, w16i, -w16r);
    BF(xrB, xiB, base + 0, base + 2, w16r, w16i);
    BF(xrB, xiB, base + 1, base + 3, w16i, -w16r);
  }
#pragma unroll
  for (int a = 0; a < 8; a += 2) {
    BF(xrA, xiA, a, a + 1, w8r, w8i);
    BF(xrB, xiB, a, a + 1, w8r, w8i);
  }

  // ---- exchange 3 -> pos 8t+j
  __syncthreads();
#pragma unroll
  for (int j = 0; j < 8; ++j) {
    const int p = PADI(((t >> 2) << 5) + u3 + 4 * j);
    reA[p] = xrA[j]; imA[p] = xiA[j];
    reB[p] = xrB[j]; imB[p] = xiB[j];
  }
  __syncthreads();
#pragma unroll
  for (int j = 0; j < 8; ++j) {
    const int p = PADI(8 * t + j);
    xrA[j] = reA[p]; xiA[j] = imA[p];
    xrB[j] = reB[p]; xiB[j] = imB[p];
  }

  // ---- round 4: stages half=2,1
#pragma unroll
  for (int base = 0; base < 8; base += 4) {
    BF(xrA, xiA, base + 0, base + 2, 1.f, 0.f);
    BF(xrA, xiA, base + 1, base + 3, 0.f, -1.f);
    BF(xrB, xiB, base + 0, base + 2, 1.f, 0.f);
    BF(xrB, xiB, base + 1, base + 3, 0.f, -1.f);
  }
#pragma unroll
  for (int a = 0; a < 8; a += 2) {
    BF(xrA, xiA, a, a + 1, 1.f, 0.f);
    BF(xrB, xiB, a, a + 1, 1.f, 0.f);
  }

  // ---- final write, then Hermitian split + product
  __syncthreads();
#pragma unroll
  for (int j = 0; j < 8; ++j) {
    const int p = PADI(8 * t + j);
    reA[p] = xrA[j]; imA[p] = xiA[j];
    reB[p] = xrB[j]; imB[p] = xiB[j];
  }
  __syncthreads();

  float2* out = Sp + (size_t)blk * L_;
#pragma unroll
  for (int i = 0; i < 8; ++i) {
    const int p = t + 256 * i;
    const int f = rev11(p);
    const int fm = (L_ - f) & (L_ - 1);
    const int pm = rev11(fm);
    const int pp = PADI(p), ppm = PADI(pm);
    const float ArA = reA[pp],  AiA = imA[pp];
    const float BrA = reA[ppm], BiA = -imA[ppm];
    const float QrA = 0.5f * (ArA + BrA), QiA = 0.5f * (AiA + BiA);
    const float CrA = 0.5f * (AiA - BiA), CiA = 0.5f * (ArA - BrA);
    const float ArB = reB[pp],  AiB = imB[pp];
    const float BrB = reB[ppm], BiB = -imB[ppm];
    const float QrB = 0.5f * (ArB + BrB), QiB = 0.5f * (AiB + BiB);
    const float CrB = 0.5f * (AiB - BiB), CiB = 0.5f * (ArB - BrB);
    const float pr = (QrA * CrA - QiA * CiA) + (QrB * CrB - QiB * CiB);
    const float pi = (QrA * CiA + QiA * CrA) + (QrB * CiB + QiB * CrB);
    out[p] = float2{pr, pi};
  }
}

// ------------------------------------------------------------------
// reduce v2: S[b][p] = sum over 256 chunks of Sp[b*256+c][p].
// 512 blocks: block = (b, pgroup of 32 p); 256 thr = 32 p x 8 c-subs
// (32 chunks each); LDS tree over the 8 partials.
// ------------------------------------------------------------------
__global__ __launch_bounds__(256) void reduce_kernel(
    const float2* __restrict__ Sp, float2* __restrict__ S)
{
  __shared__ float psr[8][33];
  __shared__ float psi[8][33];
  const int bid = (int)blockIdx.x;          // 512
  const int b = bid >> 6;
  const int pg = bid & 63;
  const int t = (int)threadIdx.x;
  const int pl = t & 31;                    // p within group
  const int cs = t >> 5;                    // 0..7
  const int p = (pg << 5) + pl;
  const float2* base = Sp + (((size_t)b << 8) << 11) + p;
  float sr = 0.f, si = 0.f;
#pragma unroll 8
  for (int c = cs * 32; c < cs * 32 + 32; ++c) {
    const float2 v = base[(size_t)c << 11];
    sr += v.x; si += v.y;
  }
  psr[cs][pl] = sr; psi[cs][pl] = si;
  __syncthreads();
  if (t < 32) {
    float tr = 0.f, ti = 0.f;
#pragma unroll
    for (int s = 0; s < 8; ++s) { tr += psr[s][t]; ti += psi[s][t]; }
    S[((size_t)b << 11) + (pg << 5) + t] = float2{tr, ti};
  }
}

// ------------------------------------------------------------------
// Inverse DIT (bit-rev in, natural out), per b, 1024 threads.
// ------------------------------------------------------------------
__global__ __launch_bounds__(1024) void ifft_kernel(
    const float2* __restrict__ S, float* __restrict__ mv)
{
  __shared__ float re[L_];
  __shared__ float im[L_];
  const int b = blockIdx.x;
  for (int p = (int)threadIdx.x; p < L_; p += 1024) {
    const float2 v = S[(size_t)b * L_ + p];
    re[p] = v.x; im[p] = v.y;
  }
  __syncthreads();
  for (int s = 1; s <= LOG2L; ++s) {
    const int half = 1 << (s - 1);
    {
      const int j = (int)threadIdx.x;
      const int pos = j & (half - 1);
      const int i0 = ((j >> (s - 1)) << s) + pos;
      const int i1 = i0 + half;
      const float ang = 3.14159265358979323846f * (float)pos / (float)half;
      float wi, wr;
      __sincosf(ang, &wi, &wr);
      const float br = re[i1], bi = im[i1];
      const float tr = br * wr - bi * wi;
      const float ti = br * wi + bi * wr;
      const float ar = re[i0], ai = im[i0];
      re[i0] = ar + tr; im[i0] = ai + ti;
      re[i1] = ar - tr; im[i1] = ai - ti;
    }
    __syncthreads();
  }
  const float scale = 1.0f / ((float)D_ * (float)L_);
  for (int l = (int)threadIdx.x; l < L_; l += 1024)
    mv[(size_t)b * L_ + l] = re[l] * scale;
}

// ------------------------------------------------------------------
// topk: 1024 threads, shuffle-reduce argmax x7, then softmax.
// ------------------------------------------------------------------
__global__ __launch_bounds__(1024) void topk_kernel(
    const float* __restrict__ mv, int* __restrict__ idx, float* __restrict__ wts)
{
  __shared__ float vals[L_];
  __shared__ float wm[16];
  __shared__ int wi[16];
  __shared__ int chosen[TOPK];
  const int t = (int)threadIdx.x;
  const int lane = t & 63, wv = t >> 6;
  float s0 = 0.f, s1 = 0.f;
#pragma unroll
  for (int b = 0; b < B_; ++b) {
    s0 += mv[(size_t)b * L_ + t];
    s1 += mv[(size_t)b * L_ + t + 1024];
  }
  vals[t] = s0; vals[t + 1024] = s1;
  __syncthreads();
  for (int kk = 0; kk < TOPK; ++kk) {
    float v0 = vals[t]; int i0 = t;
    const float v1 = vals[t + 1024];
    if (v1 > v0) { v0 = v1; i0 = t + 1024; }
#pragma unroll
    for (int off = 32; off; off >>= 1) {
      const float ov = __shfl_xor(v0, off, 64);
      const int oi = __shfl_xor(i0, off, 64);
      if (ov > v0 || (ov == v0 && oi < i0)) { v0 = ov; i0 = oi; }
    }
    if (lane == 0) { wm[wv] = v0; wi[wv] = i0; }
    __syncthreads();
    if (t == 0) {
      float m = wm[0]; int mi = wi[0];
      for (int i2 = 1; i2 < 16; ++i2)
        if (wm[i2] > m || (wm[i2] == m && wi[i2] < mi)) { m = wm[i2]; mi = wi[i2]; }
      chosen[kk] = mi; idx[kk] = mi; vals[mi] = -1e30f;
    }
    __syncthreads();
  }
  if (t < B_) {
    float w[TOPK];
    float mx = -1e30f;
#pragma unroll
    for (int kk = 0; kk < TOPK; ++kk) {
      w[kk] = mv[(size_t)t * L_ + chosen[kk]];
      mx = fmaxf(mx, w[kk]);
    }
    float sum = 0.f;
#pragma unroll
    for (int kk = 0; kk < TOPK; ++kk) { w[kk] = __expf(w[kk] - mx); sum += w[kk]; }
    const float inv = 1.0f / sum;
#pragma unroll
    for (int kk = 0; kk < TOPK; ++kk) wts[t * TOPK + kk] = w[kk] * inv;
  }
}

// ------------------------------------------------------------------
// context: 4 waves/block, one output row per wave, half8 lanes,
// XCD-swizzled (contiguous l-range per XCD).
// ------------------------------------------------------------------
__global__ __launch_bounds__(256) void context_kernel(
    const _Float16* __restrict__ v, const int* __restrict__ idx,
    const float* __restrict__ wts, _Float16* __restrict__ ctx)
{
  const int raw = (int)blockIdx.x;            // 4096
  const int wg = (raw & 7) * 512 + (raw >> 3);
  const int b = wg >> 9;                      // 512 blocks per batch
  const int l = ((wg & 511) << 2) + ((int)threadIdx.x >> 6);
  const int lane = (int)threadIdx.x & 63;
  float acc[8] = {};
#pragma unroll
  for (int kk = 0; kk < TOPK; ++kk) {
    const float w = wts[b * TOPK + kk];
    const int src = (l + idx[kk]) & (L_ - 1);
    const half8 x = *reinterpret_cast<const half8*>(v + ((size_t)(b << LOG2L) + src) * D_ + lane * 8);
#pragma unroll
    for (int j = 0; j < 8; ++j) acc[j] = fmaf(w, (float)x[j], acc[j]);
  }
  half8 o;
#pragma unroll
  for (int j = 0; j < 8; ++j) o[j] = (_Float16)acc[j];
  *reinterpret_cast<half8*>(ctx + ((size_t)(b << LOG2L) + l) * D_ + lane * 8) = o;
}

// ------------------------------------------------------------------
extern "C" void kernel_launch(void* const* d_in, const int* in_sizes, int n_in,
                              void* d_out, int out_size, void* d_ws, size_t ws_size,
                              hipStream_t stream)
{
  (void)in_sizes; (void)n_in; (void)out_size; (void)ws_size;
  const float* Q   = (const float*)d_in[0];
  const float* K   = (const float*)d_in[1];
  const float* V   = (const float*)d_in[2];
  const float* WQ  = (const float*)d_in[3];
  const float* WK  = (const float*)d_in[4];
  const float* WV  = (const float*)d_in[5];
  const float* Wfc = (const float*)d_in[6];
  float* out = (float*)d_out;

  char* ws = (char*)d_ws;
  const size_t sz_h   = (size_t)M_ * D_ * sizeof(_Float16);    // 16.78 MB
  const size_t sz_w16 = (size_t)D_ * D_ * sizeof(_Float16);    // 512 KB
  _Float16*  qT16  = (_Float16*)(ws);
  _Float16*  kT16  = (_Float16*)(ws + sz_h);
  _Float16*  vs16  = (_Float16*)(ws + 2 * sz_h);
  _Float16*  ctx16 = (_Float16*)(ws + 3 * sz_h);
  _Float16*  WQt   = (_Float16*)(ws + 4 * sz_h);
  _Float16*  WKt   = (_Float16*)(ws + 4 * sz_h + sz_w16);
  _Float16*  WVt   = (_Float16*)(ws + 4 * sz_h + 2 * sz_w16);
  _Float16*  Wfct  = (_Float16*)(ws + 4 * sz_h + 3 * sz_w16);
  float2*    S     = (float2*)(ws + 4 * sz_h + 4 * sz_w16);    // 128 KB
  float*     mv    = (float*)((char*)S + (size_t)B_ * L_ * sizeof(float2));
  int*       idx   = (int*)((char*)mv + (size_t)B_ * L_ * sizeof(float));
  float*     wts   = (float*)((char*)idx + 64);
  // Sp: 2048 slices x 2048 float2 = 33.55 MB, dedicated region
  float2*    Sp    = (float2*)(ws + 5 * sz_h + 8 * sz_w16);

  convw_kernel<<<256, 256, 0, stream>>>(WQ, WK, WV, Wfc, WQt, WKt, WVt, Wfct);

  gemm_f16_kernel<0, 3><<<NWG, 256, 0, stream>>>(Q, nullptr, WQt, nullptr, qT16);
  gemm_f16_kernel<0, 3><<<NWG, 256, 0, stream>>>(K, nullptr, WKt, nullptr, kT16);

  corr_fft_kernel<<<B_ * (D_ / 2), 256, 0, stream>>>(qT16, kT16, Sp);
  reduce_kernel<<<512, 256, 0, stream>>>(Sp, S);
  ifft_kernel<<<B_, 1024, 0, stream>>>(S, mv);
  topk_kernel<<<1, 1024, 0, stream>>>(mv, idx, wts);

  gemm_f16_kernel<0, 2><<<NWG, 256, 0, stream>>>(V, nullptr, WVt, nullptr, vs16);
  context_kernel<<<4096, 256, 0, stream>>>(vs16, idx, wts, ctx16);
  gemm_f16_kernel<1, 0><<<NWG, 256, 0, stream>>>(nullptr, ctx16, Wfct, out, nullptr);
}